// Round 1
// 513.225 us; speedup vs baseline: 1.0115x; 1.0115x over previous
//
#include <hip/hip_runtime.h>
#include <cstdint>
#include <cstddef>

#define B_   16
#define C_   512
#define N_   1024
#define M_   (B_*N_)
#define NH_  8
#define HD_  64
#define C3_  1536
#define CH_  2048

typedef __attribute__((ext_vector_type(8))) short bf16x8;
typedef __attribute__((ext_vector_type(4))) float f32x4;
typedef __attribute__((ext_vector_type(4))) unsigned short u16x4;

__device__ __forceinline__ unsigned short f2bf(float f) {
  union { float f; unsigned u; } v; v.f = f;
  unsigned r = v.u + 0x7fffu + ((v.u >> 16) & 1u);
  return (unsigned short)(r >> 16);
}
__device__ __forceinline__ float bf2f(unsigned short h) {
  union { unsigned u; float f; } v; v.u = ((unsigned)h) << 16;
  return v.f;
}
__device__ __forceinline__ unsigned f2u(float f) {
  union { float f; unsigned u; } v; v.f = f; return v.u;
}

// global -> LDS direct DMA, 16B per lane. LDS dest is wave-uniform base +
// lane*16 (linear); swizzled layouts are achieved by pre-swizzling the
// per-lane GLOBAL source address (rule 21 / m173).
#define GL16(gp, lp) \
  __builtin_amdgcn_global_load_lds( \
      (const __attribute__((address_space(1))) unsigned int*)(const void*)(gp), \
      (__attribute__((address_space(3))) unsigned int*)(void*)(lp), 16, 0, 0)

// ---------------- fused float -> bf16 conversion for all 4 weight mats ----------------
__global__ __launch_bounds__(256) void k_f2b4(
    const float* __restrict__ s0, unsigned short* __restrict__ d0,
    const float* __restrict__ s1, unsigned short* __restrict__ d1,
    const float* __restrict__ s2, unsigned short* __restrict__ d2,
    const float* __restrict__ s3, unsigned short* __restrict__ d3) {
  int blk = blockIdx.x, t = threadIdx.x;
  const float* s; unsigned short* d; int off;
  if (blk < 3072)      { s = s0; d = d0; off = blk * 256; }
  else if (blk < 4096) { s = s1; d = d1; off = (blk - 3072) * 256; }
  else if (blk < 8192) { s = s2; d = d2; off = (blk - 4096) * 256; }
  else                 { s = s3; d = d3; off = (blk - 8192) * 256; }
  int i = off + t;
  d[i] = f2bf(s[i]);
}

// ---------------- twiddle tables (bf16, stride 40), 5 tables of 32x40 ----------------
__global__ __launch_bounds__(256) void k_twid(unsigned short* __restrict__ gtab) {
  int idx = blockIdx.x * 256 + threadIdx.x;
  if (idx >= 6400) return;
  int tab = idx / 1280, rem = idx % 1280;
  int i = rem / 40, j = rem % 40;
  float v = 0.f;
  if (j < 32) {
    float th = 0.19634954084936207f * (float)((i * j) & 31);
    float s, c;
    __sincosf(th, &s, &c);
    if (tab == 0) v = c;
    else if (tab == 1) v = s;
    else if (tab == 2) v = -s;
    else {
      float wg = (j == 0 || j == 16) ? 1.f : 2.f;
      if (j >= 17) wg = 0.f;
      v = (tab == 3) ? wg * c : -wg * s;
    }
  }
  gtab[idx] = f2bf(v);
}

// ---------------- fused transpose + LayerNorm (+ optional lf/hf gates) ----------------
template<bool WITH>
__global__ __launch_bounds__(256) void k_lnt(const float* __restrict__ src,
    const float* __restrict__ w, const float* __restrict__ bia,
    const float* __restrict__ lfw, const float* __restrict__ lfb,
    const float* __restrict__ hfw, const float* __restrict__ hfb,
    const float* __restrict__ pa_s, const float* __restrict__ pa_b,
    unsigned short* __restrict__ lnout, float* __restrict__ lfout,
    float* __restrict__ hfout) {
  __shared__ unsigned short s[512 * 34];
  const int t = threadIdx.x, wv = t >> 6, l = t & 63;
  const int n0 = blockIdx.x * 32, b = blockIdx.y;
  const int cl = t >> 3;
  const int nn = (t & 7) * 4;
  #pragma unroll
  for (int k = 0; k < 16; ++k) {
    int c = k * 32 + cl;
    float4 v = *(const float4*)&src[(size_t)(b * C_ + c) * N_ + n0 + nn];
    s[c * 34 + nn]     = f2bf(v.x);
    s[c * 34 + nn + 1] = f2bf(v.y);
    s[c * 34 + nn + 2] = f2bf(v.z);
    s[c * 34 + nn + 3] = f2bf(v.w);
  }
  __syncthreads();
  float wv8[8], bv8[8];
  #pragma unroll
  for (int k = 0; k < 8; ++k) { wv8[k] = w[l + 64 * k]; bv8[k] = bia[l + 64 * k]; }
  float ps = 1.f, pb = 0.f;
  if (WITH) { ps = pa_s[0]; pb = pa_b[0]; }
  for (int ri = 0; ri < 8; ++ri) {
    const int n = wv * 8 + ri;
    const int row = b * N_ + n0 + n;
    float v[8];
    #pragma unroll
    for (int k = 0; k < 8; ++k) v[k] = bf2f(s[(l + 64 * k) * 34 + n]);
    float sm = 0.f, q = 0.f;
    #pragma unroll
    for (int k = 0; k < 8; ++k) { sm += v[k]; q += v[k] * v[k]; }
    #pragma unroll
    for (int off = 1; off < 64; off <<= 1) { sm += __shfl_xor(sm, off); q += __shfl_xor(q, off); }
    float mu = sm * (1.f / 512.f);
    float var = q * (1.f / 512.f) - mu * mu;
    float rstd = rsqrtf(var + 1e-5f);
    float ln[8];
    #pragma unroll
    for (int k = 0; k < 8; ++k) ln[k] = (v[k] - mu) * rstd * wv8[k] + bv8[k];
    #pragma unroll
    for (int k = 0; k < 8; ++k)
      lnout[(size_t)row * C_ + l + 64 * k] = f2bf(ln[k]);
    if (WITH) {
      float d[8];
      #pragma unroll
      for (int k = 0; k < 8; ++k) { float r = fmaxf(ln[k], 0.f); d[k] = ps * r * r + pb; }
      float lacc[8], hacc[8];
      #pragma unroll
      for (int h = 0; h < 8; ++h) {
        float la = 0.f, ha = 0.f;
        #pragma unroll
        for (int k = 0; k < 8; ++k) {
          la += d[k] * lfw[h * C_ + l + 64 * k];
          ha += d[k] * hfw[h * C_ + l + 64 * k];
        }
        lacc[h] = la; hacc[h] = ha;
      }
      #pragma unroll
      for (int h = 0; h < 8; ++h)
        #pragma unroll
        for (int off = 1; off < 64; off <<= 1) {
          lacc[h] += __shfl_xor(lacc[h], off);
          hacc[h] += __shfl_xor(hacc[h], off);
        }
      float lv = lacc[0], hv = hacc[0];
      #pragma unroll
      for (int h = 1; h < 8; ++h) { if (l == h) { lv = lacc[h]; hv = hacc[h]; } }
      if (l < 8) {
        lfout[(size_t)row * 8 + l] = tanhf(lv + lfb[l]);
        float z = hv + hfb[l];
        float sp = (z > 15.f) ? z : log1pf(__expf(z));
        float s2 = sp * sp;
        hfout[(size_t)row * 8 + l] = 2.f * s2 / (s2 + 0.3678f);
      }
    }
  }
}

// ---------------- GEMM v3: global_load_lds staging (m97 structure) + XCD swizzle ------
// 128x128 tile, BK=32, linear LDS [128][32] shorts, 2 barriers/K-step.
// 1D grid (nx*ny blocks, multiple of 8); XCD-chunked so consecutive logical
// blocks (sharing the A panel / B matrix) land on the same XCD's L2.
template<int EPI>
__global__ __launch_bounds__(256) void k_gemm(const unsigned short* __restrict__ A,
    const unsigned short* __restrict__ Bt, const float* __restrict__ bias,
    void* __restrict__ outv, unsigned short* __restrict__ vtg, int Nn, int K, int nx) {
  __shared__ __align__(16) unsigned short Asm[128 * 32];
  __shared__ __align__(16) unsigned short Bsm[128 * 32];
  const int t = threadIdx.x, w = t >> 6, l = t & 63;
  const int lane15 = l & 15, quad = l >> 4;
  const int cpx = gridDim.x >> 3;
  const int wgs = (blockIdx.x & 7) * cpx + (blockIdx.x >> 3);
  const int bx = wgs % nx, by = wgs / nx;
  const int n0 = bx * 128, m0 = by * 128;
  const int wm = w >> 1, wn = w & 1;
  f32x4 acc[4][4];
  #pragma unroll
  for (int i = 0; i < 4; ++i)
    #pragma unroll
    for (int j = 0; j < 4; ++j) acc[i][j] = (f32x4){0.f, 0.f, 0.f, 0.f};
  // staging: lane l of wave w covers LDS bytes [issue*4096 + w*1024 + l*16)
  // -> row = issue*64 + w*16 + (l>>2), col shorts = (l&3)*8 (linear, no pad)
  const int srow = w * 16 + (l >> 2);
  const int scol = (l & 3) * 8;
  const unsigned short* gA = A + (size_t)(m0 + srow) * K + scol;
  const unsigned short* gB = Bt + (size_t)(n0 + srow) * K + scol;
  const size_t rk64 = (size_t)64 * K;
  char* lA0 = (char*)Asm + w * 1024;
  char* lA1 = (char*)Asm + 4096 + w * 1024;
  char* lB0 = (char*)Bsm + w * 1024;
  char* lB1 = (char*)Bsm + 4096 + w * 1024;
  for (int k0 = 0; k0 < K; k0 += 32) {
    __syncthreads();                       // previous tile fully consumed
    GL16(gA + k0, lA0);
    GL16(gA + k0 + rk64, lA1);
    GL16(gB + k0, lB0);
    GL16(gB + k0 + rk64, lB1);
    __syncthreads();                       // drains vmcnt -> tile ready
    bf16x8 af[4], bg[4];
    #pragma unroll
    for (int i = 0; i < 4; ++i)
      af[i] = *(const bf16x8*)&Asm[(wm * 64 + i * 16 + lane15) * 32 + quad * 8];
    #pragma unroll
    for (int i = 0; i < 4; ++i)
      bg[i] = *(const bf16x8*)&Bsm[(wn * 64 + i * 16 + lane15) * 32 + quad * 8];
    #pragma unroll
    for (int i = 0; i < 4; ++i)
      #pragma unroll
      for (int j = 0; j < 4; ++j)
        acc[i][j] = __builtin_amdgcn_mfma_f32_16x16x32_bf16(af[i], bg[j], acc[i][j], 0, 0, 0);
  }
  #pragma unroll
  for (int i = 0; i < 4; ++i) {
    int grow = m0 + wm * 64 + i * 16 + quad * 4;
    int bq = grow >> 10, nq = grow & 1023;
    #pragma unroll
    for (int j = 0; j < 4; ++j) {
      int gcol = n0 + wn * 64 + j * 16 + lane15;
      float bs = (EPI == 0) ? 0.f : bias[gcol];
      if (EPI == 1 || EPI == 3) {
        float4 o = make_float4(acc[i][j][0] + bs, acc[i][j][1] + bs,
                               acc[i][j][2] + bs, acc[i][j][3] + bs);
        *(float4*)&((float*)outv)[((size_t)(bq * C_ + gcol) << 10) + nq] = o;
      } else if (EPI == 0) {
        u16x4 pv;
        #pragma unroll
        for (int r = 0; r < 4; ++r) {
          unsigned short hv = f2bf(acc[i][j][r]);
          pv[r] = hv;
          ((unsigned short*)outv)[(size_t)(grow + r) * Nn + gcol] = hv;
        }
        if (gcol >= 1024)
          *(u16x4*)&vtg[((size_t)(bq * C_ + gcol - 1024) << 10) + nq] = pv;
      } else {
        #pragma unroll
        for (int r = 0; r < 4; ++r) {
          float vv = acc[i][j][r] + bs;
          float e = __builtin_amdgcn_exp2f(-(2.302118073f * vv +
                                             0.1029455568f * vv * vv * vv));
          float g = vv * __builtin_amdgcn_rcpf(1.f + e);
          ((unsigned short*)outv)[(size_t)(grow + r) * Nn + gcol] = f2bf(g);
        }
      }
    }
  }
}

// ---------------- flash attention v6 ----------------
// 128 q rows/block (wave owns 32), 64-row K/V tiles staged via global_load_lds
// with XOR-swizzled layout (linear dest + pre-swizzled source), XCD-chunked
// 1D grid (1024 blocks, 128/XCD -> K/V L2-resident), setprio around MFMA.
__global__ __launch_bounds__(256, 4) void k_flash(const unsigned short* __restrict__ qkv,
    const unsigned short* __restrict__ vtg, const float* __restrict__ lf,
    const float* __restrict__ hf, const float* __restrict__ lgam,
    const float* __restrict__ hgam, unsigned short* __restrict__ y) {
  const int t = threadIdx.x, w = t >> 6, l = t & 63;
  const int lane15 = l & 15, quad = l >> 4;
  const int wg = (blockIdx.x & 7) * 128 + (blockIdx.x >> 3);   // XCD chunking
  const int qt = wg & 7;
  const int h = (wg >> 3) & 7;
  const int b = wg >> 6;
  const int q0 = qt * 128;

  __shared__ __align__(16) unsigned short kt[64 * 64];   // [n][d], stride 64, XOR-swz
  __shared__ __align__(16) unsigned short vt[64 * 64];   // [d][n], stride 64, XOR-swz
  __shared__ __align__(16) unsigned short pl[4][16 * 72];

  // Q fragments: wave w owns q rows q0 + w*32 + qh*16 + lane15
  bf16x8 aq[2][2];
  #pragma unroll
  for (int qh = 0; qh < 2; ++qh) {
    const unsigned short* qp = qkv +
        (size_t)(b * N_ + q0 + w * 32 + qh * 16 + lane15) * C3_ + h * 64 + quad * 8;
    bf16x8 r0 = *(const bf16x8*)qp;
    bf16x8 r1 = *(const bf16x8*)(qp + 32);
    #pragma unroll
    for (int i = 0; i < 8; ++i) {
      aq[qh][0][i] = (short)f2bf(0.1803368801111713f * bf2f((unsigned short)r0[i]));
      aq[qh][1][i] = (short)f2bf(0.1803368801111713f * bf2f((unsigned short)r1[i]));
    }
  }
  f32x4 O[2][4];
  #pragma unroll
  for (int qh = 0; qh < 2; ++qh)
    #pragma unroll
    for (int i = 0; i < 4; ++i) O[qh][i] = (f32x4){0.f, 0.f, 0.f, 0.f};
  float lsum[2] = {0.f, 0.f};

  // staging: issue s, lane l covers LDS bytes s*4096 + w*1024 + l*16
  //  -> phys row = s*32 + w*8 + (l>>3), phys col = (l&7)*16 bytes
  //  logical col = phys ^ ((row&7)<<4); row&7 == l>>3 here.
  const int prow = w * 8 + (l >> 3);
  const int csw = ((l & 7) ^ (l >> 3)) * 8;              // logical col in shorts
  const unsigned short* kg = qkv + (size_t)(b * N_ + prow) * C3_ + 512 + h * 64 + csw;
  const unsigned short* vg = vtg + (size_t)((b * NH_ + h) * HD_ + prow) * N_ + csw;
  char* ktb0 = (char*)kt + w * 1024;
  char* ktb1 = (char*)kt + 4096 + w * 1024;
  char* vtb0 = (char*)vt + w * 1024;
  char* vtb1 = (char*)vt + 4096 + w * 1024;
  const int swx = (lane15 & 7) * 8;                       // read-side XOR (shorts)

  for (int kti = 0; kti < 16; ++kti) {
    __syncthreads();
    const unsigned short* kr = kg + (size_t)(kti * 64) * C3_;
    GL16(kr, ktb0);
    GL16(kr + (size_t)32 * C3_, ktb1);
    const unsigned short* vr = vg + kti * 64;
    GL16(vr, vtb0);
    GL16(vr + 32 * N_, vtb1);
    __syncthreads();                                      // tile ready

    #pragma unroll
    for (int qh = 0; qh < 2; ++qh) {
      f32x4 S[4];
      __builtin_amdgcn_s_setprio(1);
      #pragma unroll
      for (int nt = 0; nt < 4; ++nt) {
        const int nrow = nt * 16 + lane15;
        bf16x8 ak0 = *(const bf16x8*)&kt[nrow * 64 + ((quad * 8) ^ swx)];
        bf16x8 ak1 = *(const bf16x8*)&kt[nrow * 64 + ((32 + quad * 8) ^ swx)];
        f32x4 z = (f32x4){0.f, 0.f, 0.f, 0.f};
        z = __builtin_amdgcn_mfma_f32_16x16x32_bf16(ak0, aq[qh][0], z, 0, 0, 0);
        z = __builtin_amdgcn_mfma_f32_16x16x32_bf16(ak1, aq[qh][1], z, 0, 0, 0);
        S[nt] = z;
      }
      __builtin_amdgcn_s_setprio(0);
      #pragma unroll
      for (int nt = 0; nt < 4; ++nt)
        #pragma unroll
        for (int r = 0; r < 4; ++r) {
          float pv = __builtin_amdgcn_exp2f(S[nt][r]);
          S[nt][r] = pv;
          lsum[qh] += pv;
        }
      #pragma unroll
      for (int nt = 0; nt < 4; ++nt) {
        unsigned lo = __builtin_amdgcn_perm(f2u(S[nt][1]), f2u(S[nt][0]), 0x07060302u);
        unsigned hi = __builtin_amdgcn_perm(f2u(S[nt][3]), f2u(S[nt][2]), 0x07060302u);
        *(uint2*)&pl[w][lane15 * 72 + nt * 16 + quad * 4] = make_uint2(lo, hi);
      }
      __builtin_amdgcn_s_setprio(1);
      #pragma unroll
      for (int nc = 0; nc < 2; ++nc) {
        bf16x8 ap = *(const bf16x8*)&pl[w][lane15 * 72 + nc * 32 + quad * 8];
        #pragma unroll
        for (int dt = 0; dt < 4; ++dt) {
          const int vrow = dt * 16 + lane15;
          bf16x8 bv = *(const bf16x8*)&vt[vrow * 64 + ((nc * 32 + quad * 8) ^ swx)];
          O[qh][dt] = __builtin_amdgcn_mfma_f32_16x16x32_bf16(ap, bv, O[qh][dt], 0, 0, 0);
        }
      }
      __builtin_amdgcn_s_setprio(0);
    }
  }

  #pragma unroll
  for (int qh = 0; qh < 2; ++qh) {
    float s = lsum[qh];
    s += __shfl_xor(s, 16);
    s += __shfl_xor(s, 32);
    float inv = 1.f / s;
    float invr[4], lfr[4], hfr[4];
    const size_t rowb = (size_t)(b * N_ + q0 + w * 32 + qh * 16 + quad * 4);
    #pragma unroll
    for (int r = 0; r < 4; ++r) {
      invr[r] = __shfl(inv, quad * 4 + r);
      lfr[r] = lf[(rowb + r) * 8 + h];
      hfr[r] = hf[(rowb + r) * 8 + h];
    }
    #pragma unroll
    for (int dt = 0; dt < 4; ++dt) {
      const int cc = h * 64 + dt * 16 + lane15;
      const float lg = lgam[cc], hg = hgam[cc];
      #pragma unroll
      for (int r = 0; r < 4; ++r) {
        float a = O[qh][dt][r] * invr[r];
        float vval = bf2f(qkv[(rowb + r) * C3_ + 1024 + cc]);
        float res = a + a * lfr[r] * lg + hfr[r] * (vval - a) * hg;
        y[(rowb + r) * C_ + cc] = f2bf(res);
      }
    }
  }
}

// ---------------- spatial mean pool per (b,c) row ----------------
__global__ __launch_bounds__(256) void k_pool(const float* __restrict__ feat,
                                              float* __restrict__ pooled) {
  int row = blockIdx.x * 4 + (threadIdx.x >> 6);
  int l = threadIdx.x & 63;
  const float4* p = (const float4*)(feat + (size_t)row * N_);
  float4 a = p[l], b4 = p[l + 64], c4 = p[l + 128], d4 = p[l + 192];
  float s = a.x + a.y + a.z + a.w + b4.x + b4.y + b4.z + b4.w +
            c4.x + c4.y + c4.z + c4.w + d4.x + d4.y + d4.z + d4.w;
  #pragma unroll
  for (int off = 1; off < 64; off <<= 1) s += __shfl_xor(s, off);
  if (l == 0) pooled[row] = s * (1.f / 1024.f);
}

// ---------------- routing: pooled(B,C) -> routing(B,64) ----------------
__global__ __launch_bounds__(256) void k_routing(const float* __restrict__ pooled,
    const float* __restrict__ rw1, const float* __restrict__ rw1s,
    const float* __restrict__ rw1b, const float* __restrict__ rw2,
    float* __restrict__ routing) {
  const int b = blockIdx.x, t = threadIdx.x;
  __shared__ float plds[512];
  __shared__ float tile[64][65];
  __shared__ float hl[64];
  plds[t] = pooled[b * 512 + t];
  plds[t + 256] = pooled[b * 512 + t + 256];
  __syncthreads();
  float acc = 0.f;
  for (int c0 = 0; c0 < 512; c0 += 64) {
    #pragma unroll
    for (int kk = 0; kk < 16; ++kk) {
      int idx = kk * 256 + t;
      tile[idx >> 6][idx & 63] = rw1[(size_t)(idx >> 6) * 512 + c0 + (idx & 63)];
    }
    __syncthreads();
    if (t < 64) {
      #pragma unroll
      for (int i = 0; i < 64; ++i) acc += plds[c0 + i] * tile[t][i];
    }
    __syncthreads();
  }
  if (t < 64) {
    float r = fmaxf(acc, 0.f);
    hl[t] = rw1s[0] * r * r + rw1b[0];
  }
  __syncthreads();
  if (t < 64) {
    float r2 = 0.f;
    #pragma unroll
    for (int j = 0; j < 64; ++j) r2 += hl[j] * rw2[(size_t)t * 64 + j];
    routing[b * 64 + t] = tanhf(r2);
  }
}

// ---------------- per-plane 32x32 rfft2 * dyn -> irfft2 via MFMA, fused residual ------
__global__ __launch_bounds__(256) void k_freq(const float* __restrict__ feat,
    const float* __restrict__ routing, const float* __restrict__ fwtab,
    const unsigned short* __restrict__ gtab, const float* __restrict__ res,
    const float* __restrict__ gamma, float* __restrict__ outp) {
  const int c = blockIdx.x, b = blockIdx.y, t = threadIdx.x;
  const int g = c >> 5, cc = c & 31;
  const int w = t >> 6, l = t & 63;
  const int lane15 = l & 15, quad = l >> 4;
  const int mt = w & 1, nt = w >> 1;
  __shared__ __align__(16) unsigned short Xbf[32 * 40];
  __shared__ __align__(16) float p[32 * 36];
  __shared__ __align__(16) unsigned short Tabs[6400];
  __shared__ __align__(16) unsigned short pl1r[32 * 40], pl1i[32 * 40];
  __shared__ __align__(16) unsigned short pl2r[32 * 40], pl2i[32 * 40];
  __shared__ __align__(16) unsigned short pl3r[32 * 40], pl3i[32 * 40];
  __shared__ float Ms[1024];
  const size_t base = (size_t)(b * C_ + c) * N_;

  {
    float4 v = ((const float4*)(feat + base))[t];
    int hh = t >> 3, w4 = (t & 7) * 4;
    *(float4*)&p[hh * 36 + w4] = v;
    u16x4 xb = { f2bf(v.x), f2bf(v.y), f2bf(v.z), f2bf(v.w) };
    *(u16x4*)&Xbf[hh * 40 + w4] = xb;
  }
  {
    const uint4* src = (const uint4*)gtab;
    uint4* dst = (uint4*)Tabs;
    #pragma unroll
    for (int k = 0; k < 4; ++k) {
      int o = k * 256 + t;
      if (o < 800) dst[o] = src[o];
    }
  }
  {
    float r0 = routing[b * 64 + g * 4 + 0];
    float r1 = routing[b * 64 + g * 4 + 1];
    float r2 = routing[b * 64 + g * 4 + 2];
    float r3 = routing[b * 64 + g * 4 + 3];
    const float* fb = fwtab + (size_t)cc * 544;
    #pragma unroll
    for (int k = 0; k < 4; ++k) {
      int o = k * 256 + t;
      int fh = o >> 5, fw = o & 31;
      float mv = 0.f;
      if (fw < 17) {
        int fi = fh * 17 + fw;
        mv = (r0 * fb[fi] + r1 * fb[17408 + fi] + r2 * fb[34816 + fi] +
              r3 * fb[52224 + fi]) * (1.f / 1024.f);
      }
      Ms[o] = mv;
    }
  }
  __syncthreads();

  const unsigned short* Tc  = Tabs;
  const unsigned short* Ts  = Tabs + 1280;
  const unsigned short* Tsn = Tabs + 2560;
  const unsigned short* Tcw = Tabs + 3840;
  const unsigned short* Tsw = Tabs + 5120;
  const int arow = (mt * 16 + lane15) * 40 + quad * 8;
  const int brow = (nt * 16 + lane15) * 40 + quad * 8;
  const int prow = (nt * 16 + lane15) * 40 + mt * 16 + quad * 4;
  const f32x4 zz = (f32x4){0.f, 0.f, 0.f, 0.f};

  {
    bf16x8 aX = *(const bf16x8*)&Xbf[arow];
    bf16x8 bC = *(const bf16x8*)&Tc[brow];
    bf16x8 bS = *(const bf16x8*)&Tsn[brow];
    f32x4 re = __builtin_amdgcn_mfma_f32_16x16x32_bf16(aX, bC, zz, 0, 0, 0);
    f32x4 im = __builtin_amdgcn_mfma_f32_16x16x32_bf16(aX, bS, zz, 0, 0, 0);
    uint2 pr = make_uint2(__builtin_amdgcn_perm(f2u(re[1]), f2u(re[0]), 0x07060302u),
                          __builtin_amdgcn_perm(f2u(re[3]), f2u(re[2]), 0x07060302u));
    uint2 pi = make_uint2(__builtin_amdgcn_perm(f2u(im[1]), f2u(im[0]), 0x07060302u),
                          __builtin_amdgcn_perm(f2u(im[3]), f2u(im[2]), 0x07060302u));
    *(uint2*)&pl1r[prow] = pr;
    *(uint2*)&pl1i[prow] = pi;
  }
  __syncthreads();
  {
    bf16x8 aC = *(const bf16x8*)&Tc[arow];
    bf16x8 aS = *(const bf16x8*)&Ts[arow];
    bf16x8 aN = *(const bf16x8*)&Tsn[arow];
    bf16x8 bR = *(const bf16x8*)&pl1r[brow];
    bf16x8 bI = *(const bf16x8*)&pl1i[brow];
    f32x4 er = __builtin_amdgcn_mfma_f32_16x16x32_bf16(aC, bR, zz, 0, 0, 0);
    er = __builtin_amdgcn_mfma_f32_16x16x32_bf16(aS, bI, er, 0, 0, 0);
    f32x4 ei = __builtin_amdgcn_mfma_f32_16x16x32_bf16(aC, bI, zz, 0, 0, 0);
    ei = __builtin_amdgcn_mfma_f32_16x16x32_bf16(aN, bR, ei, 0, 0, 0);
    #pragma unroll
    for (int r = 0; r < 4; ++r) {
      float mk = Ms[(mt * 16 + quad * 4 + r) * 32 + nt * 16 + lane15];
      er[r] *= mk; ei[r] *= mk;
    }
    uint2 pr = make_uint2(__builtin_amdgcn_perm(f2u(er[1]), f2u(er[0]), 0x07060302u),
                          __builtin_amdgcn_perm(f2u(er[3]), f2u(er[2]), 0x07060302u));
    uint2 pi = make_uint2(__builtin_amdgcn_perm(f2u(ei[1]), f2u(ei[0]), 0x07060302u),
                          __builtin_amdgcn_perm(f2u(ei[3]), f2u(ei[2]), 0x07060302u));
    *(uint2*)&pl2r[prow] = pr;
    *(uint2*)&pl2i[prow] = pi;
  }
  __syncthreads();
  {
    bf16x8 aR = *(const bf16x8*)&pl2r[arow];
    bf16x8 aI = *(const bf16x8*)&pl2i[arow];
    bf16x8 bC = *(const bf16x8*)&Tc[brow];
    bf16x8 bS = *(const bf16x8*)&Ts[brow];
    bf16x8 bN = *(const bf16x8*)&Tsn[brow];
    f32x4 zr = __builtin_amdgcn_mfma_f32_16x16x32_bf16(aR, bC, zz, 0, 0, 0);
    zr = __builtin_amdgcn_mfma_f32_16x16x32_bf16(aI, bN, zr, 0, 0, 0);
    f32x4 zi = __builtin_amdgcn_mfma_f32_16x16x32_bf16(aI, bC, zz, 0, 0, 0);
    zi = __builtin_amdgcn_mfma_f32_16x16x32_bf16(aR, bS, zi, 0, 0, 0);
    uint2 pr = make_uint2(__builtin_amdgcn_perm(f2u(zr[1]), f2u(zr[0]), 0x07060302u),
                          __builtin_amdgcn_perm(f2u(zr[3]), f2u(zr[2]), 0x07060302u));
    uint2 pi = make_uint2(__builtin_amdgcn_perm(f2u(zi[1]), f2u(zi[0]), 0x07060302u),
                          __builtin_amdgcn_perm(f2u(zi[3]), f2u(zi[2]), 0x07060302u));
    *(uint2*)&pl3r[prow] = pr;
    *(uint2*)&pl3i[prow] = pi;
  }
  __syncthreads();
  {
    bf16x8 aC = *(const bf16x8*)&Tcw[arow];
    bf16x8 aS = *(const bf16x8*)&Tsw[arow];
    bf16x8 bR = *(const bf16x8*)&pl3r[brow];
    bf16x8 bI = *(const bf16x8*)&pl3i[brow];
    f32x4 y = __builtin_amdgcn_mfma_f32_16x16x32_bf16(aC, bR, zz, 0, 0, 0);
    y = __builtin_amdgcn_mfma_f32_16x16x32_bf16(aS, bI, y, 0, 0, 0);
    int hh = nt * 16 + lane15, w0 = mt * 16 + quad * 4;
    float4 fp = *(const float4*)&p[hh * 36 + w0];
    float4 rp = *(const float4*)&res[base + hh * 32 + w0];
    float gv = gamma[c];
    float4 o = make_float4(rp.x + gv * (y[0] + fp.x), rp.y + gv * (y[1] + fp.y),
                           rp.z + gv * (y[2] + fp.z), rp.w + gv * (y[3] + fp.w));
    *(float4*)&outp[base + hh * 32 + w0] = o;
  }
}

// =============================== launch ===============================
extern "C" void kernel_launch(void* const* d_in, const int* in_sizes, int n_in,
                              void* d_out, int out_size, void* d_ws, size_t ws_size,
                              hipStream_t stream) {
  (void)in_sizes; (void)n_in; (void)out_size; (void)ws_size;
  const float* x      = (const float*)d_in[0];
  const float* n1w    = (const float*)d_in[1];
  const float* n1b    = (const float*)d_in[2];
  const float* qkv_w  = (const float*)d_in[3];
  const float* proj_w = (const float*)d_in[4];
  const float* proj_b = (const float*)d_in[5];
  const float* pa_s   = (const float*)d_in[6];
  const float* pa_b   = (const float*)d_in[7];
  const float* lf_w   = (const float*)d_in[8];
  const float* lf_b   = (const float*)d_in[9];
  const float* hf_w   = (const float*)d_in[10];
  const float* hf_b   = (const float*)d_in[11];
  const float* lf_g   = (const float*)d_in[12];
  const float* hf_g   = (const float*)d_in[13];
  const float* f1rw1w = (const float*)d_in[14];
  const float* f1rw1s = (const float*)d_in[15];
  const float* f1rw1b = (const float*)d_in[16];
  const float* f1rw2w = (const float*)d_in[17];
  const float* f1fw   = (const float*)d_in[18];
  const float* gamma1 = (const float*)d_in[19];
  const float* n2w    = (const float*)d_in[20];
  const float* n2b    = (const float*)d_in[21];
  const float* fc1w   = (const float*)d_in[22];
  const float* fc1b   = (const float*)d_in[23];
  const float* fc2w   = (const float*)d_in[24];
  const float* fc2b   = (const float*)d_in[25];
  const float* f2rw1w = (const float*)d_in[26];
  const float* f2rw1s = (const float*)d_in[27];
  const float* f2rw1b = (const float*)d_in[28];
  const float* f2rw2w = (const float*)d_in[29];
  const float* f2fw   = (const float*)d_in[30];
  const float* gamma2 = (const float*)d_in[31];

  char* ws = (char*)d_ws;
  float*          tokens = (float*)(ws + 0);              // tokens_f1 (B,C,N)
  float*          f1buf  = (float*)(ws + 33554432ULL);
  float*          f2buf  = (float*)(ws + 67108864ULL);
  unsigned short* regA   = (unsigned short*)(ws + 134217728ULL);
  unsigned short* abuf   = (unsigned short*)(ws + 201326592ULL);
  float*          lfbuf  = (float*)(ws + 218103808ULL);
  float*          hfbuf  = (float*)(ws + 218628096ULL);
  float*          pooled = (float*)(ws + 219152384ULL);
  float*          routing= (float*)(ws + 219185152ULL);
  unsigned short* wq     = (unsigned short*)(ws + 219189248ULL);
  unsigned short* wp     = (unsigned short*)(ws + 220762112ULL);
  unsigned short* w1     = (unsigned short*)(ws + 221286400ULL);
  unsigned short* w2     = (unsigned short*)(ws + 223383552ULL);
  unsigned short* gtab   = (unsigned short*)(ws + 225480704ULL);
  unsigned short* vtg    = (unsigned short*)f1buf;

  k_f2b4<<<12288, 256, 0, stream>>>(qkv_w, wq, proj_w, wp, fc1w, w1, fc2w, w2);
  k_twid<<<25, 256, 0, stream>>>(gtab);

  // LN1 fused with transpose (reads x in B,C,N) + gates
  k_lnt<true><<<dim3(32, 16), 256, 0, stream>>>(x, n1w, n1b, lf_w, lf_b, hf_w, hf_b,
                                                pa_s, pa_b, abuf, lfbuf, hfbuf);
  // GEMMs on XCD-chunked 1D grids (nwg multiple of 8)
  k_gemm<0><<<1536, 256, 0, stream>>>(abuf, wq, n1b, regA, vtg, C3_, C_, 12);
  k_flash<<<1024, 256, 0, stream>>>(regA, vtg, lfbuf, hfbuf, lf_g, hf_g, abuf);
  k_gemm<1><<<512, 256, 0, stream>>>(abuf, wp, proj_b, f2buf, nullptr, C_, C_, 4);
  k_pool<<<2048, 256, 0, stream>>>(f2buf, pooled);
  k_routing<<<16, 256, 0, stream>>>(pooled, f1rw1w, f1rw1s, f1rw1b, f1rw2w, routing);
  // freq1 + fused residual: tokens = x + gamma1*(dft + feat)
  k_freq<<<dim3(512, 16), 256, 0, stream>>>(f2buf, routing, f1fw, gtab, x, gamma1, tokens);
  // LN2 fused with transpose (reads tokens in B,C,N)
  k_lnt<false><<<dim3(32, 16), 256, 0, stream>>>(tokens, n2w, n2b, nullptr, nullptr,
                                                 nullptr, nullptr, nullptr, nullptr,
                                                 abuf, nullptr, nullptr);
  k_gemm<2><<<2048, 256, 0, stream>>>(abuf, w1, fc1b, regA, nullptr, CH_, C_, 16);
  k_gemm<3><<<512, 256, 0, stream>>>(regA, w2, fc2b, f2buf, nullptr, C_, CH_, 4);
  k_pool<<<2048, 256, 0, stream>>>(f2buf, pooled);
  k_routing<<<16, 256, 0, stream>>>(pooled, f2rw1w, f2rw1s, f2rw1b, f2rw2w, routing);
  // freq2 + fused residual: out = tokens + gamma2*(dft + feat)
  k_freq<<<dim3(512, 16), 256, 0, stream>>>(f2buf, routing, f2fw, gtab, tokens, gamma2,
                                            (float*)d_out);
}

// Round 2
// 503.148 us; speedup vs baseline: 1.0317x; 1.0200x over previous
//
#include <hip/hip_runtime.h>
#include <cstdint>
#include <cstddef>

#define B_   16
#define C_   512
#define N_   1024
#define M_   (B_*N_)
#define NH_  8
#define HD_  64
#define C3_  1536
#define CH_  2048

typedef __attribute__((ext_vector_type(8))) short bf16x8;
typedef __attribute__((ext_vector_type(4))) float f32x4;
typedef __attribute__((ext_vector_type(4))) unsigned short u16x4;

__device__ __forceinline__ unsigned short f2bf(float f) {
  union { float f; unsigned u; } v; v.f = f;
  unsigned r = v.u + 0x7fffu + ((v.u >> 16) & 1u);
  return (unsigned short)(r >> 16);
}
__device__ __forceinline__ float bf2f(unsigned short h) {
  union { unsigned u; float f; } v; v.u = ((unsigned)h) << 16;
  return v.f;
}
__device__ __forceinline__ unsigned f2u(float f) {
  union { float f; unsigned u; } v; v.f = f; return v.u;
}

// global -> LDS direct DMA, 16B per lane. LDS dest is wave-uniform base +
// lane*16 (linear); swizzled layouts via pre-swizzled GLOBAL source (m173).
#define GL16(gp, lp) \
  __builtin_amdgcn_global_load_lds( \
      (const __attribute__((address_space(1))) unsigned int*)(const void*)(gp), \
      (__attribute__((address_space(3))) unsigned int*)(void*)(lp), 16, 0, 0)

// ---------------- fused float -> bf16 conversion for all 4 weight mats ----------------
__global__ __launch_bounds__(256) void k_f2b4(
    const float* __restrict__ s0, unsigned short* __restrict__ d0,
    const float* __restrict__ s1, unsigned short* __restrict__ d1,
    const float* __restrict__ s2, unsigned short* __restrict__ d2,
    const float* __restrict__ s3, unsigned short* __restrict__ d3) {
  int blk = blockIdx.x, t = threadIdx.x;
  const float* s; unsigned short* d; int off;
  if (blk < 3072)      { s = s0; d = d0; off = blk * 256; }
  else if (blk < 4096) { s = s1; d = d1; off = (blk - 3072) * 256; }
  else if (blk < 8192) { s = s2; d = d2; off = (blk - 4096) * 256; }
  else                 { s = s3; d = d3; off = (blk - 8192) * 256; }
  int i = off + t;
  d[i] = f2bf(s[i]);
}

// ---------------- twiddle tables + zero the two pooled accumulators ----------------
__global__ __launch_bounds__(256) void k_twid(unsigned short* __restrict__ gtab,
                                              float* __restrict__ p1,
                                              float* __restrict__ p2) {
  int idx = blockIdx.x * 256 + threadIdx.x;
  if (idx < 6400) {
    int tab = idx / 1280, rem = idx % 1280;
    int i = rem / 40, j = rem % 40;
    float v = 0.f;
    if (j < 32) {
      float th = 0.19634954084936207f * (float)((i * j) & 31);
      float s, c;
      __sincosf(th, &s, &c);
      if (tab == 0) v = c;
      else if (tab == 1) v = s;
      else if (tab == 2) v = -s;
      else {
        float wg = (j == 0 || j == 16) ? 1.f : 2.f;
        if (j >= 17) wg = 0.f;
        v = (tab == 3) ? wg * c : -wg * s;
      }
    }
    gtab[idx] = f2bf(v);
  } else if (idx < 14592) {
    p1[idx - 6400] = 0.f;
  } else if (idx < 22784) {
    p2[idx - 14592] = 0.f;
  }
}

// ---------------- fused transpose + LayerNorm (+ optional lf/hf gates) ----------------
template<bool WITH>
__global__ __launch_bounds__(256) void k_lnt(const float* __restrict__ src,
    const float* __restrict__ w, const float* __restrict__ bia,
    const float* __restrict__ lfw, const float* __restrict__ lfb,
    const float* __restrict__ hfw, const float* __restrict__ hfb,
    const float* __restrict__ pa_s, const float* __restrict__ pa_b,
    unsigned short* __restrict__ lnout, float* __restrict__ lfout,
    float* __restrict__ hfout) {
  __shared__ unsigned short s[512 * 34];
  const int t = threadIdx.x, wv = t >> 6, l = t & 63;
  const int n0 = blockIdx.x * 32, b = blockIdx.y;
  const int cl = t >> 3;
  const int nn = (t & 7) * 4;
  #pragma unroll
  for (int k = 0; k < 16; ++k) {
    int c = k * 32 + cl;
    float4 v = *(const float4*)&src[(size_t)(b * C_ + c) * N_ + n0 + nn];
    s[c * 34 + nn]     = f2bf(v.x);
    s[c * 34 + nn + 1] = f2bf(v.y);
    s[c * 34 + nn + 2] = f2bf(v.z);
    s[c * 34 + nn + 3] = f2bf(v.w);
  }
  __syncthreads();
  float wv8[8], bv8[8];
  #pragma unroll
  for (int k = 0; k < 8; ++k) { wv8[k] = w[l + 64 * k]; bv8[k] = bia[l + 64 * k]; }
  float ps = 1.f, pb = 0.f;
  if (WITH) { ps = pa_s[0]; pb = pa_b[0]; }
  for (int ri = 0; ri < 8; ++ri) {
    const int n = wv * 8 + ri;
    const int row = b * N_ + n0 + n;
    float v[8];
    #pragma unroll
    for (int k = 0; k < 8; ++k) v[k] = bf2f(s[(l + 64 * k) * 34 + n]);
    float sm = 0.f, q = 0.f;
    #pragma unroll
    for (int k = 0; k < 8; ++k) { sm += v[k]; q += v[k] * v[k]; }
    #pragma unroll
    for (int off = 1; off < 64; off <<= 1) { sm += __shfl_xor(sm, off); q += __shfl_xor(q, off); }
    float mu = sm * (1.f / 512.f);
    float var = q * (1.f / 512.f) - mu * mu;
    float rstd = rsqrtf(var + 1e-5f);
    float ln[8];
    #pragma unroll
    for (int k = 0; k < 8; ++k) ln[k] = (v[k] - mu) * rstd * wv8[k] + bv8[k];
    #pragma unroll
    for (int k = 0; k < 8; ++k)
      lnout[(size_t)row * C_ + l + 64 * k] = f2bf(ln[k]);
    if (WITH) {
      float d[8];
      #pragma unroll
      for (int k = 0; k < 8; ++k) { float r = fmaxf(ln[k], 0.f); d[k] = ps * r * r + pb; }
      float lacc[8], hacc[8];
      #pragma unroll
      for (int h = 0; h < 8; ++h) {
        float la = 0.f, ha = 0.f;
        #pragma unroll
        for (int k = 0; k < 8; ++k) {
          la += d[k] * lfw[h * C_ + l + 64 * k];
          ha += d[k] * hfw[h * C_ + l + 64 * k];
        }
        lacc[h] = la; hacc[h] = ha;
      }
      #pragma unroll
      for (int h = 0; h < 8; ++h)
        #pragma unroll
        for (int off = 1; off < 64; off <<= 1) {
          lacc[h] += __shfl_xor(lacc[h], off);
          hacc[h] += __shfl_xor(hacc[h], off);
        }
      float lv = lacc[0], hv = hacc[0];
      #pragma unroll
      for (int h = 1; h < 8; ++h) { if (l == h) { lv = lacc[h]; hv = hacc[h]; } }
      if (l < 8) {
        lfout[(size_t)row * 8 + l] = tanhf(lv + lfb[l]);
        float z = hv + hfb[l];
        float sp = (z > 15.f) ? z : log1pf(__expf(z));
        float s2 = sp * sp;
        hfout[(size_t)row * 8 + l] = 2.f * s2 / (s2 + 0.3678f);
      }
    }
  }
}

// ---------------- GEMM v4: double-buffered global_load_lds prefetch pipeline ----------
// 128x128 tile, BK=32. Per K-step: stage(next) -> compute(cur) -> barrier.
// The prefetch overlaps the MFMA phase (T3 depth-1 recipe, m248-validated).
// EPI 1/3 additionally accumulate the spatial mean pool via atomics (vtg = pooled).
template<int EPI>
__global__ __launch_bounds__(256) void k_gemm(const unsigned short* __restrict__ A,
    const unsigned short* __restrict__ Bt, const float* __restrict__ bias,
    void* __restrict__ outv, unsigned short* __restrict__ vtg, int Nn, int K, int nx) {
  __shared__ __align__(16) unsigned short Asm[2 * 128 * 32];
  __shared__ __align__(16) unsigned short Bsm[2 * 128 * 32];
  const int t = threadIdx.x, w = t >> 6, l = t & 63;
  const int lane15 = l & 15, quad = l >> 4;
  const int cpx = gridDim.x >> 3;
  const int wgs = (blockIdx.x & 7) * cpx + (blockIdx.x >> 3);
  const int bx = wgs % nx, by = wgs / nx;
  const int n0 = bx * 128, m0 = by * 128;
  const int wm = w >> 1, wn = w & 1;
  f32x4 acc[4][4];
  #pragma unroll
  for (int i = 0; i < 4; ++i)
    #pragma unroll
    for (int j = 0; j < 4; ++j) acc[i][j] = (f32x4){0.f, 0.f, 0.f, 0.f};
  const int srow = w * 16 + (l >> 2);
  const int scol = (l & 3) * 8;
  const unsigned short* gA = A + (size_t)(m0 + srow) * K + scol;
  const unsigned short* gB = Bt + (size_t)(n0 + srow) * K + scol;
  const size_t rk64 = (size_t)64 * K;
  auto stage = [&](int bufi, int k0) {
    char* a = (char*)Asm + bufi * 8192 + w * 1024;
    char* bb = (char*)Bsm + bufi * 8192 + w * 1024;
    GL16(gA + k0, a);
    GL16(gA + k0 + rk64, a + 4096);
    GL16(gB + k0, bb);
    GL16(gB + k0 + rk64, bb + 4096);
  };
  stage(0, 0);
  __syncthreads();
  for (int k0 = 0; k0 < K; k0 += 32) {
    const int cur = (k0 >> 5) & 1;
    if (k0 + 32 < K) stage(cur ^ 1, k0 + 32);
    const unsigned short* As = Asm + cur * 4096;
    const unsigned short* Bs = Bsm + cur * 4096;
    bf16x8 af[4], bg[4];
    #pragma unroll
    for (int i = 0; i < 4; ++i)
      af[i] = *(const bf16x8*)&As[(wm * 64 + i * 16 + lane15) * 32 + quad * 8];
    #pragma unroll
    for (int i = 0; i < 4; ++i)
      bg[i] = *(const bf16x8*)&Bs[(wn * 64 + i * 16 + lane15) * 32 + quad * 8];
    #pragma unroll
    for (int i = 0; i < 4; ++i)
      #pragma unroll
      for (int j = 0; j < 4; ++j)
        acc[i][j] = __builtin_amdgcn_mfma_f32_16x16x32_bf16(af[i], bg[j], acc[i][j], 0, 0, 0);
    __syncthreads();
  }
  float psum[4] = {0.f, 0.f, 0.f, 0.f};
  #pragma unroll
  for (int i = 0; i < 4; ++i) {
    int grow = m0 + wm * 64 + i * 16 + quad * 4;
    int bq = grow >> 10, nq = grow & 1023;
    #pragma unroll
    for (int j = 0; j < 4; ++j) {
      int gcol = n0 + wn * 64 + j * 16 + lane15;
      float bs = (EPI == 0) ? 0.f : bias[gcol];
      if (EPI == 1 || EPI == 3) {
        float4 o = make_float4(acc[i][j][0] + bs, acc[i][j][1] + bs,
                               acc[i][j][2] + bs, acc[i][j][3] + bs);
        psum[j] += o.x + o.y + o.z + o.w;
        *(float4*)&((float*)outv)[((size_t)(bq * C_ + gcol) << 10) + nq] = o;
      } else if (EPI == 0) {
        u16x4 pv;
        #pragma unroll
        for (int r = 0; r < 4; ++r) {
          unsigned short hv = f2bf(acc[i][j][r]);
          pv[r] = hv;
          ((unsigned short*)outv)[(size_t)(grow + r) * Nn + gcol] = hv;
        }
        if (gcol >= 1024)
          *(u16x4*)&vtg[((size_t)(bq * C_ + gcol - 1024) << 10) + nq] = pv;
      } else {
        #pragma unroll
        for (int r = 0; r < 4; ++r) {
          float vv = acc[i][j][r] + bs;
          float e = __builtin_amdgcn_exp2f(-(2.302118073f * vv +
                                             0.1029455568f * vv * vv * vv));
          float g = vv * __builtin_amdgcn_rcpf(1.f + e);
          ((unsigned short*)outv)[(size_t)(grow + r) * Nn + gcol] = f2bf(g);
        }
      }
    }
  }
  if (EPI == 1 || EPI == 3) {
    float* pooled = (float*)vtg;
    const int bq = m0 >> 10;
    #pragma unroll
    for (int j = 0; j < 4; ++j) {
      float v = psum[j] * (1.f / 1024.f);
      v += __shfl_xor(v, 16);
      v += __shfl_xor(v, 32);
      if (quad == 0) {
        int gcol = n0 + wn * 64 + j * 16 + lane15;
        atomicAdd(&pooled[bq * C_ + gcol], v);
      }
    }
  }
}

// ---------------- flash attention v7: double-buffered K/V prefetch pipeline ----------
// 128 q rows/block, 64-row K/V tiles. Per tile: stage(next) -> compute(cur) ->
// barrier; prefetch latency hides under QK/softmax/PV. LDS exactly 40 KiB ->
// 4 blocks/CU with grid 1024 fully resident.
__global__ __launch_bounds__(256, 4) void k_flash(const unsigned short* __restrict__ qkv,
    const unsigned short* __restrict__ vtg, const float* __restrict__ lf,
    const float* __restrict__ hf, const float* __restrict__ lgam,
    const float* __restrict__ hgam, unsigned short* __restrict__ y) {
  const int t = threadIdx.x, w = t >> 6, l = t & 63;
  const int lane15 = l & 15, quad = l >> 4;
  const int wg = (blockIdx.x & 7) * 128 + (blockIdx.x >> 3);   // XCD chunking
  const int qt = wg & 7;
  const int h = (wg >> 3) & 7;
  const int b = wg >> 6;
  const int q0 = qt * 128;

  __shared__ __align__(16) unsigned short kt[2 * 64 * 64];   // 16 KiB, XOR-swz
  __shared__ __align__(16) unsigned short vt[2 * 64 * 64];   // 16 KiB, XOR-swz
  __shared__ __align__(16) unsigned short pl[4][16 * 64];    // 8 KiB, XOR-swz

  bf16x8 aq[2][2];
  #pragma unroll
  for (int qh = 0; qh < 2; ++qh) {
    const unsigned short* qp = qkv +
        (size_t)(b * N_ + q0 + w * 32 + qh * 16 + lane15) * C3_ + h * 64 + quad * 8;
    bf16x8 r0 = *(const bf16x8*)qp;
    bf16x8 r1 = *(const bf16x8*)(qp + 32);
    #pragma unroll
    for (int i = 0; i < 8; ++i) {
      aq[qh][0][i] = (short)f2bf(0.1803368801111713f * bf2f((unsigned short)r0[i]));
      aq[qh][1][i] = (short)f2bf(0.1803368801111713f * bf2f((unsigned short)r1[i]));
    }
  }
  f32x4 O[2][4];
  #pragma unroll
  for (int qh = 0; qh < 2; ++qh)
    #pragma unroll
    for (int i = 0; i < 4; ++i) O[qh][i] = (f32x4){0.f, 0.f, 0.f, 0.f};
  float lsum[2] = {0.f, 0.f};

  // staging: lane covers phys row w*8+(l>>3), phys col (l&7)*16B; logical col
  // = phys ^ ((row&7)<<4); row&7 == l>>3 -> pre-swizzle the global source.
  const int prow = w * 8 + (l >> 3);
  const int csw = ((l & 7) ^ (l >> 3)) * 8;
  const unsigned short* kg = qkv + (size_t)(b * N_ + prow) * C3_ + 512 + h * 64 + csw;
  const unsigned short* vg = vtg + (size_t)((b * NH_ + h) * HD_ + prow) * N_ + csw;
  const int swx = (lane15 & 7) * 8;                       // read-side XOR (shorts)

  auto stage = [&](int bufi, int tile) {
    const unsigned short* kr = kg + (size_t)(tile * 64) * C3_;
    const unsigned short* vr = vg + tile * 64;
    char* kb = (char*)kt + bufi * 8192 + w * 1024;
    char* vb = (char*)vt + bufi * 8192 + w * 1024;
    GL16(kr, kb);
    GL16(kr + (size_t)32 * C3_, kb + 4096);
    GL16(vr, vb);
    GL16(vr + 32 * N_, vb + 4096);
  };

  char* plb = (char*)pl[w] + lane15 * 128;
  const int plx = (lane15 & 7) << 4;                      // pl row XOR (bytes)

  stage(0, 0);
  __syncthreads();

  for (int kti = 0; kti < 16; ++kti) {
    if (kti < 15) stage((kti + 1) & 1, kti + 1);
    const unsigned short* ktc = kt + (kti & 1) * 4096;
    const unsigned short* vtc = vt + (kti & 1) * 4096;

    #pragma unroll
    for (int qh = 0; qh < 2; ++qh) {
      f32x4 S[4];
      __builtin_amdgcn_s_setprio(1);
      #pragma unroll
      for (int nt = 0; nt < 4; ++nt) {
        const int nrow = nt * 16 + lane15;
        bf16x8 ak0 = *(const bf16x8*)&ktc[nrow * 64 + ((quad * 8) ^ swx)];
        bf16x8 ak1 = *(const bf16x8*)&ktc[nrow * 64 + ((32 + quad * 8) ^ swx)];
        f32x4 z = (f32x4){0.f, 0.f, 0.f, 0.f};
        z = __builtin_amdgcn_mfma_f32_16x16x32_bf16(ak0, aq[qh][0], z, 0, 0, 0);
        z = __builtin_amdgcn_mfma_f32_16x16x32_bf16(ak1, aq[qh][1], z, 0, 0, 0);
        S[nt] = z;
      }
      __builtin_amdgcn_s_setprio(0);
      #pragma unroll
      for (int nt = 0; nt < 4; ++nt)
        #pragma unroll
        for (int r = 0; r < 4; ++r) {
          float pv = __builtin_amdgcn_exp2f(S[nt][r]);
          S[nt][r] = pv;
          lsum[qh] += pv;
        }
      #pragma unroll
      for (int nt = 0; nt < 4; ++nt) {
        unsigned lo = __builtin_amdgcn_perm(f2u(S[nt][1]), f2u(S[nt][0]), 0x07060302u);
        unsigned hi = __builtin_amdgcn_perm(f2u(S[nt][3]), f2u(S[nt][2]), 0x07060302u);
        *(uint2*)(plb + ((nt * 32 + quad * 8) ^ plx)) = make_uint2(lo, hi);
      }
      __builtin_amdgcn_s_setprio(1);
      #pragma unroll
      for (int nc = 0; nc < 2; ++nc) {
        bf16x8 ap = *(const bf16x8*)(plb + ((nc * 64 + quad * 16) ^ plx));
        #pragma unroll
        for (int dt = 0; dt < 4; ++dt) {
          const int vrow = dt * 16 + lane15;
          bf16x8 bv = *(const bf16x8*)&vtc[vrow * 64 + ((nc * 32 + quad * 8) ^ swx)];
          O[qh][dt] = __builtin_amdgcn_mfma_f32_16x16x32_bf16(ap, bv, O[qh][dt], 0, 0, 0);
        }
      }
      __builtin_amdgcn_s_setprio(0);
    }
    __syncthreads();
  }

  #pragma unroll
  for (int qh = 0; qh < 2; ++qh) {
    float s = lsum[qh];
    s += __shfl_xor(s, 16);
    s += __shfl_xor(s, 32);
    float inv = 1.f / s;
    float invr[4], lfr[4], hfr[4];
    const size_t rowb = (size_t)(b * N_ + q0 + w * 32 + qh * 16 + quad * 4);
    #pragma unroll
    for (int r = 0; r < 4; ++r) {
      invr[r] = __shfl(inv, quad * 4 + r);
      lfr[r] = lf[(rowb + r) * 8 + h];
      hfr[r] = hf[(rowb + r) * 8 + h];
    }
    #pragma unroll
    for (int dt = 0; dt < 4; ++dt) {
      const int cc = h * 64 + dt * 16 + lane15;
      const float lg = lgam[cc], hg = hgam[cc];
      #pragma unroll
      for (int r = 0; r < 4; ++r) {
        float a = O[qh][dt][r] * invr[r];
        float vval = bf2f(qkv[(rowb + r) * C3_ + 1024 + cc]);
        float res = a + a * lfr[r] * lg + hfr[r] * (vval - a) * hg;
        y[(rowb + r) * C_ + cc] = f2bf(res);
      }
    }
  }
}

// ---------------- routing: pooled(B,C) -> routing(B,64) ----------------
__global__ __launch_bounds__(256) void k_routing(const float* __restrict__ pooled,
    const float* __restrict__ rw1, const float* __restrict__ rw1s,
    const float* __restrict__ rw1b, const float* __restrict__ rw2,
    float* __restrict__ routing) {
  const int b = blockIdx.x, t = threadIdx.x;
  __shared__ float plds[512];
  __shared__ float tile[64][65];
  __shared__ float hl[64];
  plds[t] = pooled[b * 512 + t];
  plds[t + 256] = pooled[b * 512 + t + 256];
  __syncthreads();
  float acc = 0.f;
  for (int c0 = 0; c0 < 512; c0 += 64) {
    #pragma unroll
    for (int kk = 0; kk < 16; ++kk) {
      int idx = kk * 256 + t;
      tile[idx >> 6][idx & 63] = rw1[(size_t)(idx >> 6) * 512 + c0 + (idx & 63)];
    }
    __syncthreads();
    if (t < 64) {
      #pragma unroll
      for (int i = 0; i < 64; ++i) acc += plds[c0 + i] * tile[t][i];
    }
    __syncthreads();
  }
  if (t < 64) {
    float r = fmaxf(acc, 0.f);
    hl[t] = rw1s[0] * r * r + rw1b[0];
  }
  __syncthreads();
  if (t < 64) {
    float r2 = 0.f;
    #pragma unroll
    for (int j = 0; j < 64; ++j) r2 += hl[j] * rw2[(size_t)t * 64 + j];
    routing[b * 64 + t] = tanhf(r2);
  }
}

// ---------------- per-plane 32x32 rfft2 * dyn -> irfft2 via MFMA, fused residual ------
__global__ __launch_bounds__(256) void k_freq(const float* __restrict__ feat,
    const float* __restrict__ routing, const float* __restrict__ fwtab,
    const unsigned short* __restrict__ gtab, const float* __restrict__ res,
    const float* __restrict__ gamma, float* __restrict__ outp) {
  const int c = blockIdx.x, b = blockIdx.y, t = threadIdx.x;
  const int g = c >> 5, cc = c & 31;
  const int w = t >> 6, l = t & 63;
  const int lane15 = l & 15, quad = l >> 4;
  const int mt = w & 1, nt = w >> 1;
  __shared__ __align__(16) unsigned short Xbf[32 * 40];
  __shared__ __align__(16) float p[32 * 36];
  __shared__ __align__(16) unsigned short Tabs[6400];
  __shared__ __align__(16) unsigned short pl1r[32 * 40], pl1i[32 * 40];
  __shared__ __align__(16) unsigned short pl2r[32 * 40], pl2i[32 * 40];
  __shared__ __align__(16) unsigned short pl3r[32 * 40], pl3i[32 * 40];
  __shared__ float Ms[1024];
  const size_t base = (size_t)(b * C_ + c) * N_;

  {
    float4 v = ((const float4*)(feat + base))[t];
    int hh = t >> 3, w4 = (t & 7) * 4;
    *(float4*)&p[hh * 36 + w4] = v;
    u16x4 xb = { f2bf(v.x), f2bf(v.y), f2bf(v.z), f2bf(v.w) };
    *(u16x4*)&Xbf[hh * 40 + w4] = xb;
  }
  {
    const uint4* src = (const uint4*)gtab;
    uint4* dst = (uint4*)Tabs;
    #pragma unroll
    for (int k = 0; k < 4; ++k) {
      int o = k * 256 + t;
      if (o < 800) dst[o] = src[o];
    }
  }
  {
    float r0 = routing[b * 64 + g * 4 + 0];
    float r1 = routing[b * 64 + g * 4 + 1];
    float r2 = routing[b * 64 + g * 4 + 2];
    float r3 = routing[b * 64 + g * 4 + 3];
    const float* fb = fwtab + (size_t)cc * 544;
    #pragma unroll
    for (int k = 0; k < 4; ++k) {
      int o = k * 256 + t;
      int fh = o >> 5, fw = o & 31;
      float mv = 0.f;
      if (fw < 17) {
        int fi = fh * 17 + fw;
        mv = (r0 * fb[fi] + r1 * fb[17408 + fi] + r2 * fb[34816 + fi] +
              r3 * fb[52224 + fi]) * (1.f / 1024.f);
      }
      Ms[o] = mv;
    }
  }
  __syncthreads();

  const unsigned short* Tc  = Tabs;
  const unsigned short* Ts  = Tabs + 1280;
  const unsigned short* Tsn = Tabs + 2560;
  const unsigned short* Tcw = Tabs + 3840;
  const unsigned short* Tsw = Tabs + 5120;
  const int arow = (mt * 16 + lane15) * 40 + quad * 8;
  const int brow = (nt * 16 + lane15) * 40 + quad * 8;
  const int prow = (nt * 16 + lane15) * 40 + mt * 16 + quad * 4;
  const f32x4 zz = (f32x4){0.f, 0.f, 0.f, 0.f};

  {
    bf16x8 aX = *(const bf16x8*)&Xbf[arow];
    bf16x8 bC = *(const bf16x8*)&Tc[brow];
    bf16x8 bS = *(const bf16x8*)&Tsn[brow];
    f32x4 re = __builtin_amdgcn_mfma_f32_16x16x32_bf16(aX, bC, zz, 0, 0, 0);
    f32x4 im = __builtin_amdgcn_mfma_f32_16x16x32_bf16(aX, bS, zz, 0, 0, 0);
    uint2 pr = make_uint2(__builtin_amdgcn_perm(f2u(re[1]), f2u(re[0]), 0x07060302u),
                          __builtin_amdgcn_perm(f2u(re[3]), f2u(re[2]), 0x07060302u));
    uint2 pi = make_uint2(__builtin_amdgcn_perm(f2u(im[1]), f2u(im[0]), 0x07060302u),
                          __builtin_amdgcn_perm(f2u(im[3]), f2u(im[2]), 0x07060302u));
    *(uint2*)&pl1r[prow] = pr;
    *(uint2*)&pl1i[prow] = pi;
  }
  __syncthreads();
  {
    bf16x8 aC = *(const bf16x8*)&Tc[arow];
    bf16x8 aS = *(const bf16x8*)&Ts[arow];
    bf16x8 aN = *(const bf16x8*)&Tsn[arow];
    bf16x8 bR = *(const bf16x8*)&pl1r[brow];
    bf16x8 bI = *(const bf16x8*)&pl1i[brow];
    f32x4 er = __builtin_amdgcn_mfma_f32_16x16x32_bf16(aC, bR, zz, 0, 0, 0);
    er = __builtin_amdgcn_mfma_f32_16x16x32_bf16(aS, bI, er, 0, 0, 0);
    f32x4 ei = __builtin_amdgcn_mfma_f32_16x16x32_bf16(aC, bI, zz, 0, 0, 0);
    ei = __builtin_amdgcn_mfma_f32_16x16x32_bf16(aN, bR, ei, 0, 0, 0);
    #pragma unroll
    for (int r = 0; r < 4; ++r) {
      float mk = Ms[(mt * 16 + quad * 4 + r) * 32 + nt * 16 + lane15];
      er[r] *= mk; ei[r] *= mk;
    }
    uint2 pr = make_uint2(__builtin_amdgcn_perm(f2u(er[1]), f2u(er[0]), 0x07060302u),
                          __builtin_amdgcn_perm(f2u(er[3]), f2u(er[2]), 0x07060302u));
    uint2 pi = make_uint2(__builtin_amdgcn_perm(f2u(ei[1]), f2u(ei[0]), 0x07060302u),
                          __builtin_amdgcn_perm(f2u(ei[3]), f2u(ei[2]), 0x07060302u));
    *(uint2*)&pl2r[prow] = pr;
    *(uint2*)&pl2i[prow] = pi;
  }
  __syncthreads();
  {
    bf16x8 aR = *(const bf16x8*)&pl2r[arow];
    bf16x8 aI = *(const bf16x8*)&pl2i[arow];
    bf16x8 bC = *(const bf16x8*)&Tc[brow];
    bf16x8 bS = *(const bf16x8*)&Ts[brow];
    bf16x8 bN = *(const bf16x8*)&Tsn[brow];
    f32x4 zr = __builtin_amdgcn_mfma_f32_16x16x32_bf16(aR, bC, zz, 0, 0, 0);
    zr = __builtin_amdgcn_mfma_f32_16x16x32_bf16(aI, bN, zr, 0, 0, 0);
    f32x4 zi = __builtin_amdgcn_mfma_f32_16x16x32_bf16(aI, bC, zz, 0, 0, 0);
    zi = __builtin_amdgcn_mfma_f32_16x16x32_bf16(aR, bS, zi, 0, 0, 0);
    uint2 pr = make_uint2(__builtin_amdgcn_perm(f2u(zr[1]), f2u(zr[0]), 0x07060302u),
                          __builtin_amdgcn_perm(f2u(zr[3]), f2u(zr[2]), 0x07060302u));
    uint2 pi = make_uint2(__builtin_amdgcn_perm(f2u(zi[1]), f2u(zi[0]), 0x07060302u),
                          __builtin_amdgcn_perm(f2u(zi[3]), f2u(zi[2]), 0x07060302u));
    *(uint2*)&pl3r[prow] = pr;
    *(uint2*)&pl3i[prow] = pi;
  }
  __syncthreads();
  {
    bf16x8 aC = *(const bf16x8*)&Tcw[arow];
    bf16x8 aS = *(const bf16x8*)&Tsw[arow];
    bf16x8 bR = *(const bf16x8*)&pl3r[brow];
    bf16x8 bI = *(const bf16x8*)&pl3i[brow];
    f32x4 y = __builtin_amdgcn_mfma_f32_16x16x32_bf16(aC, bR, zz, 0, 0, 0);
    y = __builtin_amdgcn_mfma_f32_16x16x32_bf16(aS, bI, y, 0, 0, 0);
    int hh = nt * 16 + lane15, w0 = mt * 16 + quad * 4;
    float4 fp = *(const float4*)&p[hh * 36 + w0];
    float4 rp = *(const float4*)&res[base + hh * 32 + w0];
    float gv = gamma[c];
    float4 o = make_float4(rp.x + gv * (y[0] + fp.x), rp.y + gv * (y[1] + fp.y),
                           rp.z + gv * (y[2] + fp.z), rp.w + gv * (y[3] + fp.w));
    *(float4*)&outp[base + hh * 32 + w0] = o;
  }
}

// =============================== launch ===============================
extern "C" void kernel_launch(void* const* d_in, const int* in_sizes, int n_in,
                              void* d_out, int out_size, void* d_ws, size_t ws_size,
                              hipStream_t stream) {
  (void)in_sizes; (void)n_in; (void)out_size; (void)ws_size;
  const float* x      = (const float*)d_in[0];
  const float* n1w    = (const float*)d_in[1];
  const float* n1b    = (const float*)d_in[2];
  const float* qkv_w  = (const float*)d_in[3];
  const float* proj_w = (const float*)d_in[4];
  const float* proj_b = (const float*)d_in[5];
  const float* pa_s   = (const float*)d_in[6];
  const float* pa_b   = (const float*)d_in[7];
  const float* lf_w   = (const float*)d_in[8];
  const float* lf_b   = (const float*)d_in[9];
  const float* hf_w   = (const float*)d_in[10];
  const float* hf_b   = (const float*)d_in[11];
  const float* lf_g   = (const float*)d_in[12];
  const float* hf_g   = (const float*)d_in[13];
  const float* f1rw1w = (const float*)d_in[14];
  const float* f1rw1s = (const float*)d_in[15];
  const float* f1rw1b = (const float*)d_in[16];
  const float* f1rw2w = (const float*)d_in[17];
  const float* f1fw   = (const float*)d_in[18];
  const float* gamma1 = (const float*)d_in[19];
  const float* n2w    = (const float*)d_in[20];
  const float* n2b    = (const float*)d_in[21];
  const float* fc1w   = (const float*)d_in[22];
  const float* fc1b   = (const float*)d_in[23];
  const float* fc2w   = (const float*)d_in[24];
  const float* fc2b   = (const float*)d_in[25];
  const float* f2rw1w = (const float*)d_in[26];
  const float* f2rw1s = (const float*)d_in[27];
  const float* f2rw1b = (const float*)d_in[28];
  const float* f2rw2w = (const float*)d_in[29];
  const float* f2fw   = (const float*)d_in[30];
  const float* gamma2 = (const float*)d_in[31];

  char* ws = (char*)d_ws;
  float*          tokens = (float*)(ws + 0);              // tokens_f1 (B,C,N)
  float*          f1buf  = (float*)(ws + 33554432ULL);
  float*          f2buf  = (float*)(ws + 67108864ULL);
  unsigned short* regA   = (unsigned short*)(ws + 134217728ULL);
  unsigned short* abuf   = (unsigned short*)(ws + 201326592ULL);
  float*          lfbuf  = (float*)(ws + 218103808ULL);
  float*          hfbuf  = (float*)(ws + 218628096ULL);
  float*          pooled = (float*)(ws + 219152384ULL);
  float*          routing= (float*)(ws + 219185152ULL);
  unsigned short* wq     = (unsigned short*)(ws + 219189248ULL);
  unsigned short* wp     = (unsigned short*)(ws + 220762112ULL);
  unsigned short* w1     = (unsigned short*)(ws + 221286400ULL);
  unsigned short* w2     = (unsigned short*)(ws + 223383552ULL);
  unsigned short* gtab   = (unsigned short*)(ws + 225480704ULL);
  unsigned short* vtg    = (unsigned short*)f1buf;
  float*          pooled2= (float*)(ws + 50331648ULL);    // spare half of f1buf window

  k_f2b4<<<12288, 256, 0, stream>>>(qkv_w, wq, proj_w, wp, fc1w, w1, fc2w, w2);
  k_twid<<<89, 256, 0, stream>>>(gtab, pooled, pooled2);

  // LN1 fused with transpose (reads x in B,C,N) + gates
  k_lnt<true><<<dim3(32, 16), 256, 0, stream>>>(x, n1w, n1b, lf_w, lf_b, hf_w, hf_b,
                                                pa_s, pa_b, abuf, lfbuf, hfbuf);
  // GEMMs on XCD-chunked 1D grids (nwg multiple of 8)
  k_gemm<0><<<1536, 256, 0, stream>>>(abuf, wq, n1b, regA, vtg, C3_, C_, 12);
  k_flash<<<1024, 256, 0, stream>>>(regA, vtg, lfbuf, hfbuf, lf_g, hf_g, abuf);
  k_gemm<1><<<512, 256, 0, stream>>>(abuf, wp, proj_b, f2buf,
                                     (unsigned short*)pooled, C_, C_, 4);
  k_routing<<<16, 256, 0, stream>>>(pooled, f1rw1w, f1rw1s, f1rw1b, f1rw2w, routing);
  // freq1 + fused residual: tokens = x + gamma1*(dft + feat)
  k_freq<<<dim3(512, 16), 256, 0, stream>>>(f2buf, routing, f1fw, gtab, x, gamma1, tokens);
  // LN2 fused with transpose (reads tokens in B,C,N)
  k_lnt<false><<<dim3(32, 16), 256, 0, stream>>>(tokens, n2w, n2b, nullptr, nullptr,
                                                 nullptr, nullptr, nullptr, nullptr,
                                                 abuf, nullptr, nullptr);
  k_gemm<2><<<2048, 256, 0, stream>>>(abuf, w1, fc1b, regA, nullptr, CH_, C_, 16);
  k_gemm<3><<<512, 256, 0, stream>>>(regA, w2, fc2b, f2buf,
                                     (unsigned short*)pooled2, C_, CH_, 4);
  k_routing<<<16, 256, 0, stream>>>(pooled2, f2rw1w, f2rw1s, f2rw1b, f2rw2w, routing);
  // freq2 + fused residual: out = tokens + gamma2*(dft + feat)
  k_freq<<<dim3(512, 16), 256, 0, stream>>>(f2buf, routing, f2fw, gtab, tokens, gamma2,
                                            (float*)d_out);
}

// Round 3
// 487.309 us; speedup vs baseline: 1.0652x; 1.0325x over previous
//
#include <hip/hip_runtime.h>
#include <cstdint>
#include <cstddef>

#define B_   16
#define C_   512
#define N_   1024
#define M_   (B_*N_)
#define NH_  8
#define HD_  64
#define C3_  1536
#define CH_  2048

typedef __attribute__((ext_vector_type(8))) short bf16x8;
typedef __attribute__((ext_vector_type(4))) float f32x4;
typedef __attribute__((ext_vector_type(4))) unsigned short u16x4;

__device__ __forceinline__ unsigned short f2bf(float f) {
  union { float f; unsigned u; } v; v.f = f;
  unsigned r = v.u + 0x7fffu + ((v.u >> 16) & 1u);
  return (unsigned short)(r >> 16);
}
__device__ __forceinline__ float bf2f(unsigned short h) {
  union { unsigned u; float f; } v; v.u = ((unsigned)h) << 16;
  return v.f;
}
__device__ __forceinline__ unsigned f2u(float f) {
  union { float f; unsigned u; } v; v.f = f; return v.u;
}

// global -> LDS direct DMA, 16B per lane. LDS dest is wave-uniform base +
// lane*16 (linear); swizzled layouts via pre-swizzled GLOBAL source (m173).
#define GL16(gp, lp) \
  __builtin_amdgcn_global_load_lds( \
      (const __attribute__((address_space(1))) unsigned int*)(const void*)(gp), \
      (__attribute__((address_space(3))) unsigned int*)(void*)(lp), 16, 0, 0)

// ---------------- fused float -> bf16 conversion for all 4 weight mats ----------------
__global__ __launch_bounds__(256) void k_f2b4(
    const float* __restrict__ s0, unsigned short* __restrict__ d0,
    const float* __restrict__ s1, unsigned short* __restrict__ d1,
    const float* __restrict__ s2, unsigned short* __restrict__ d2,
    const float* __restrict__ s3, unsigned short* __restrict__ d3) {
  int blk = blockIdx.x, t = threadIdx.x;
  const float* s; unsigned short* d; int off;
  if (blk < 3072)      { s = s0; d = d0; off = blk * 256; }
  else if (blk < 4096) { s = s1; d = d1; off = (blk - 3072) * 256; }
  else if (blk < 8192) { s = s2; d = d2; off = (blk - 4096) * 256; }
  else                 { s = s3; d = d3; off = (blk - 8192) * 256; }
  int i = off + t;
  d[i] = f2bf(s[i]);
}

// ---------------- twiddle tables + zero the two pooled accumulators ----------------
__global__ __launch_bounds__(256) void k_twid(unsigned short* __restrict__ gtab,
                                              float* __restrict__ p1,
                                              float* __restrict__ p2) {
  int idx = blockIdx.x * 256 + threadIdx.x;
  if (idx < 6400) {
    int tab = idx / 1280, rem = idx % 1280;
    int i = rem / 40, j = rem % 40;
    float v = 0.f;
    if (j < 32) {
      float th = 0.19634954084936207f * (float)((i * j) & 31);
      float s, c;
      __sincosf(th, &s, &c);
      if (tab == 0) v = c;
      else if (tab == 1) v = s;
      else if (tab == 2) v = -s;
      else {
        float wg = (j == 0 || j == 16) ? 1.f : 2.f;
        if (j >= 17) wg = 0.f;
        v = (tab == 3) ? wg * c : -wg * s;
      }
    }
    gtab[idx] = f2bf(v);
  } else if (idx < 14592) {
    p1[idx - 6400] = 0.f;
  } else if (idx < 22784) {
    p2[idx - 14592] = 0.f;
  }
}

// ---------------- fused transpose + LayerNorm (+ optional lf/hf gates) ----------------
template<bool WITH>
__global__ __launch_bounds__(256) void k_lnt(const float* __restrict__ src,
    const float* __restrict__ w, const float* __restrict__ bia,
    const float* __restrict__ lfw, const float* __restrict__ lfb,
    const float* __restrict__ hfw, const float* __restrict__ hfb,
    const float* __restrict__ pa_s, const float* __restrict__ pa_b,
    unsigned short* __restrict__ lnout, float* __restrict__ lfout,
    float* __restrict__ hfout) {
  __shared__ unsigned short s[512 * 34];
  const int t = threadIdx.x, wv = t >> 6, l = t & 63;
  const int n0 = blockIdx.x * 32, b = blockIdx.y;
  const int cl = t >> 3;
  const int nn = (t & 7) * 4;
  #pragma unroll
  for (int k = 0; k < 16; ++k) {
    int c = k * 32 + cl;
    float4 v = *(const float4*)&src[(size_t)(b * C_ + c) * N_ + n0 + nn];
    s[c * 34 + nn]     = f2bf(v.x);
    s[c * 34 + nn + 1] = f2bf(v.y);
    s[c * 34 + nn + 2] = f2bf(v.z);
    s[c * 34 + nn + 3] = f2bf(v.w);
  }
  __syncthreads();
  float wv8[8], bv8[8];
  #pragma unroll
  for (int k = 0; k < 8; ++k) { wv8[k] = w[l + 64 * k]; bv8[k] = bia[l + 64 * k]; }
  float ps = 1.f, pb = 0.f;
  if (WITH) { ps = pa_s[0]; pb = pa_b[0]; }
  for (int ri = 0; ri < 8; ++ri) {
    const int n = wv * 8 + ri;
    const int row = b * N_ + n0 + n;
    float v[8];
    #pragma unroll
    for (int k = 0; k < 8; ++k) v[k] = bf2f(s[(l + 64 * k) * 34 + n]);
    float sm = 0.f, q = 0.f;
    #pragma unroll
    for (int k = 0; k < 8; ++k) { sm += v[k]; q += v[k] * v[k]; }
    #pragma unroll
    for (int off = 1; off < 64; off <<= 1) { sm += __shfl_xor(sm, off); q += __shfl_xor(q, off); }
    float mu = sm * (1.f / 512.f);
    float var = q * (1.f / 512.f) - mu * mu;
    float rstd = rsqrtf(var + 1e-5f);
    float ln[8];
    #pragma unroll
    for (int k = 0; k < 8; ++k) ln[k] = (v[k] - mu) * rstd * wv8[k] + bv8[k];
    #pragma unroll
    for (int k = 0; k < 8; ++k)
      lnout[(size_t)row * C_ + l + 64 * k] = f2bf(ln[k]);
    if (WITH) {
      float d[8];
      #pragma unroll
      for (int k = 0; k < 8; ++k) { float r = fmaxf(ln[k], 0.f); d[k] = ps * r * r + pb; }
      float lacc[8], hacc[8];
      #pragma unroll
      for (int h = 0; h < 8; ++h) {
        float la = 0.f, ha = 0.f;
        #pragma unroll
        for (int k = 0; k < 8; ++k) {
          la += d[k] * lfw[h * C_ + l + 64 * k];
          ha += d[k] * hfw[h * C_ + l + 64 * k];
        }
        lacc[h] = la; hacc[h] = ha;
      }
      #pragma unroll
      for (int h = 0; h < 8; ++h)
        #pragma unroll
        for (int off = 1; off < 64; off <<= 1) {
          lacc[h] += __shfl_xor(lacc[h], off);
          hacc[h] += __shfl_xor(hacc[h], off);
        }
      float lv = lacc[0], hv = hacc[0];
      #pragma unroll
      for (int h = 1; h < 8; ++h) { if (l == h) { lv = lacc[h]; hv = hacc[h]; } }
      if (l < 8) {
        lfout[(size_t)row * 8 + l] = tanhf(lv + lfb[l]);
        float z = hv + hfb[l];
        float sp = (z > 15.f) ? z : log1pf(__expf(z));
        float s2 = sp * sp;
        hfout[(size_t)row * 8 + l] = 2.f * s2 / (s2 + 0.3678f);
      }
    }
  }
}

// ---------------- GEMM v4: double-buffered global_load_lds prefetch pipeline ----------
// 128x128 tile, BK=32. Per K-step: stage(next) -> compute(cur) -> barrier.
// EPI 1/3 write bf16 feat + accumulate the spatial mean pool (vtg = pooled f32).
template<int EPI>
__global__ __launch_bounds__(256) void k_gemm(const unsigned short* __restrict__ A,
    const unsigned short* __restrict__ Bt, const float* __restrict__ bias,
    void* __restrict__ outv, unsigned short* __restrict__ vtg, int Nn, int K, int nx) {
  __shared__ __align__(16) unsigned short Asm[2 * 128 * 32];
  __shared__ __align__(16) unsigned short Bsm[2 * 128 * 32];
  const int t = threadIdx.x, w = t >> 6, l = t & 63;
  const int lane15 = l & 15, quad = l >> 4;
  const int cpx = gridDim.x >> 3;
  const int wgs = (blockIdx.x & 7) * cpx + (blockIdx.x >> 3);
  const int bx = wgs % nx, by = wgs / nx;
  const int n0 = bx * 128, m0 = by * 128;
  const int wm = w >> 1, wn = w & 1;
  f32x4 acc[4][4];
  #pragma unroll
  for (int i = 0; i < 4; ++i)
    #pragma unroll
    for (int j = 0; j < 4; ++j) acc[i][j] = (f32x4){0.f, 0.f, 0.f, 0.f};
  const int srow = w * 16 + (l >> 2);
  const int scol = (l & 3) * 8;
  const unsigned short* gA = A + (size_t)(m0 + srow) * K + scol;
  const unsigned short* gB = Bt + (size_t)(n0 + srow) * K + scol;
  const size_t rk64 = (size_t)64 * K;
  auto stage = [&](int bufi, int k0) {
    char* a = (char*)Asm + bufi * 8192 + w * 1024;
    char* bb = (char*)Bsm + bufi * 8192 + w * 1024;
    GL16(gA + k0, a);
    GL16(gA + k0 + rk64, a + 4096);
    GL16(gB + k0, bb);
    GL16(gB + k0 + rk64, bb + 4096);
  };
  stage(0, 0);
  __syncthreads();
  for (int k0 = 0; k0 < K; k0 += 32) {
    const int cur = (k0 >> 5) & 1;
    if (k0 + 32 < K) stage(cur ^ 1, k0 + 32);
    const unsigned short* As = Asm + cur * 4096;
    const unsigned short* Bs = Bsm + cur * 4096;
    bf16x8 af[4], bg[4];
    #pragma unroll
    for (int i = 0; i < 4; ++i)
      af[i] = *(const bf16x8*)&As[(wm * 64 + i * 16 + lane15) * 32 + quad * 8];
    #pragma unroll
    for (int i = 0; i < 4; ++i)
      bg[i] = *(const bf16x8*)&Bs[(wn * 64 + i * 16 + lane15) * 32 + quad * 8];
    #pragma unroll
    for (int i = 0; i < 4; ++i)
      #pragma unroll
      for (int j = 0; j < 4; ++j)
        acc[i][j] = __builtin_amdgcn_mfma_f32_16x16x32_bf16(af[i], bg[j], acc[i][j], 0, 0, 0);
    __syncthreads();
  }
  float psum[4] = {0.f, 0.f, 0.f, 0.f};
  #pragma unroll
  for (int i = 0; i < 4; ++i) {
    int grow = m0 + wm * 64 + i * 16 + quad * 4;
    int bq = grow >> 10, nq = grow & 1023;
    #pragma unroll
    for (int j = 0; j < 4; ++j) {
      int gcol = n0 + wn * 64 + j * 16 + lane15;
      float bs = (EPI == 0) ? 0.f : bias[gcol];
      if (EPI == 1 || EPI == 3) {
        float4 o = make_float4(acc[i][j][0] + bs, acc[i][j][1] + bs,
                               acc[i][j][2] + bs, acc[i][j][3] + bs);
        psum[j] += o.x + o.y + o.z + o.w;
        u16x4 pv = { f2bf(o.x), f2bf(o.y), f2bf(o.z), f2bf(o.w) };
        *(u16x4*)&((unsigned short*)outv)[((size_t)(bq * C_ + gcol) << 10) + nq] = pv;
      } else if (EPI == 0) {
        u16x4 pv;
        #pragma unroll
        for (int r = 0; r < 4; ++r) {
          unsigned short hv = f2bf(acc[i][j][r]);
          pv[r] = hv;
          ((unsigned short*)outv)[(size_t)(grow + r) * Nn + gcol] = hv;
        }
        if (gcol >= 1024)
          *(u16x4*)&vtg[((size_t)(bq * C_ + gcol - 1024) << 10) + nq] = pv;
      } else {
        #pragma unroll
        for (int r = 0; r < 4; ++r) {
          float vv = acc[i][j][r] + bs;
          float e = __builtin_amdgcn_exp2f(-(2.302118073f * vv +
                                             0.1029455568f * vv * vv * vv));
          float g = vv * __builtin_amdgcn_rcpf(1.f + e);
          ((unsigned short*)outv)[(size_t)(grow + r) * Nn + gcol] = f2bf(g);
        }
      }
    }
  }
  if (EPI == 1 || EPI == 3) {
    float* pooled = (float*)vtg;
    const int bq = m0 >> 10;
    #pragma unroll
    for (int j = 0; j < 4; ++j) {
      float v = psum[j] * (1.f / 1024.f);
      v += __shfl_xor(v, 16);
      v += __shfl_xor(v, 32);
      if (quad == 0) {
        int gcol = n0 + wn * 64 + j * 16 + lane15;
        atomicAdd(&pooled[bq * C_ + gcol], v);
      }
    }
  }
}

// ---------------- flash attention v6 (reverted known-good structure) ----------------
// 128 q rows/block, single-buffered 64-row K/V tiles via global_load_lds with
// XOR-swizzled layout, XCD-chunked 1D grid, setprio around MFMA clusters.
__global__ __launch_bounds__(256, 4) void k_flash(const unsigned short* __restrict__ qkv,
    const unsigned short* __restrict__ vtg, const float* __restrict__ lf,
    const float* __restrict__ hf, const float* __restrict__ lgam,
    const float* __restrict__ hgam, unsigned short* __restrict__ y) {
  const int t = threadIdx.x, w = t >> 6, l = t & 63;
  const int lane15 = l & 15, quad = l >> 4;
  const int wg = (blockIdx.x & 7) * 128 + (blockIdx.x >> 3);   // XCD chunking
  const int qt = wg & 7;
  const int h = (wg >> 3) & 7;
  const int b = wg >> 6;
  const int q0 = qt * 128;

  __shared__ __align__(16) unsigned short kt[64 * 64];   // [n][d], stride 64, XOR-swz
  __shared__ __align__(16) unsigned short vt[64 * 64];   // [d][n], stride 64, XOR-swz
  __shared__ __align__(16) unsigned short pl[4][16 * 72];

  bf16x8 aq[2][2];
  #pragma unroll
  for (int qh = 0; qh < 2; ++qh) {
    const unsigned short* qp = qkv +
        (size_t)(b * N_ + q0 + w * 32 + qh * 16 + lane15) * C3_ + h * 64 + quad * 8;
    bf16x8 r0 = *(const bf16x8*)qp;
    bf16x8 r1 = *(const bf16x8*)(qp + 32);
    #pragma unroll
    for (int i = 0; i < 8; ++i) {
      aq[qh][0][i] = (short)f2bf(0.1803368801111713f * bf2f((unsigned short)r0[i]));
      aq[qh][1][i] = (short)f2bf(0.1803368801111713f * bf2f((unsigned short)r1[i]));
    }
  }
  f32x4 O[2][4];
  #pragma unroll
  for (int qh = 0; qh < 2; ++qh)
    #pragma unroll
    for (int i = 0; i < 4; ++i) O[qh][i] = (f32x4){0.f, 0.f, 0.f, 0.f};
  float lsum[2] = {0.f, 0.f};

  // staging: lane covers phys row w*8+(l>>3), phys col (l&7)*16B; logical col
  // = phys ^ ((row&7)<<4); row&7 == l>>3 -> pre-swizzle the global source.
  const int prow = w * 8 + (l >> 3);
  const int csw = ((l & 7) ^ (l >> 3)) * 8;
  const unsigned short* kg = qkv + (size_t)(b * N_ + prow) * C3_ + 512 + h * 64 + csw;
  const unsigned short* vg = vtg + (size_t)((b * NH_ + h) * HD_ + prow) * N_ + csw;
  char* ktb0 = (char*)kt + w * 1024;
  char* ktb1 = (char*)kt + 4096 + w * 1024;
  char* vtb0 = (char*)vt + w * 1024;
  char* vtb1 = (char*)vt + 4096 + w * 1024;
  const int swx = (lane15 & 7) * 8;                       // read-side XOR (shorts)

  for (int kti = 0; kti < 16; ++kti) {
    __syncthreads();
    const unsigned short* kr = kg + (size_t)(kti * 64) * C3_;
    GL16(kr, ktb0);
    GL16(kr + (size_t)32 * C3_, ktb1);
    const unsigned short* vr = vg + kti * 64;
    GL16(vr, vtb0);
    GL16(vr + 32 * N_, vtb1);
    __syncthreads();                                      // tile ready

    #pragma unroll
    for (int qh = 0; qh < 2; ++qh) {
      f32x4 S[4];
      __builtin_amdgcn_s_setprio(1);
      #pragma unroll
      for (int nt = 0; nt < 4; ++nt) {
        const int nrow = nt * 16 + lane15;
        bf16x8 ak0 = *(const bf16x8*)&kt[nrow * 64 + ((quad * 8) ^ swx)];
        bf16x8 ak1 = *(const bf16x8*)&kt[nrow * 64 + ((32 + quad * 8) ^ swx)];
        f32x4 z = (f32x4){0.f, 0.f, 0.f, 0.f};
        z = __builtin_amdgcn_mfma_f32_16x16x32_bf16(ak0, aq[qh][0], z, 0, 0, 0);
        z = __builtin_amdgcn_mfma_f32_16x16x32_bf16(ak1, aq[qh][1], z, 0, 0, 0);
        S[nt] = z;
      }
      __builtin_amdgcn_s_setprio(0);
      #pragma unroll
      for (int nt = 0; nt < 4; ++nt)
        #pragma unroll
        for (int r = 0; r < 4; ++r) {
          float pv = __builtin_amdgcn_exp2f(S[nt][r]);
          S[nt][r] = pv;
          lsum[qh] += pv;
        }
      #pragma unroll
      for (int nt = 0; nt < 4; ++nt) {
        unsigned lo = __builtin_amdgcn_perm(f2u(S[nt][1]), f2u(S[nt][0]), 0x07060302u);
        unsigned hi = __builtin_amdgcn_perm(f2u(S[nt][3]), f2u(S[nt][2]), 0x07060302u);
        *(uint2*)&pl[w][lane15 * 72 + nt * 16 + quad * 4] = make_uint2(lo, hi);
      }
      __builtin_amdgcn_s_setprio(1);
      #pragma unroll
      for (int nc = 0; nc < 2; ++nc) {
        bf16x8 ap = *(const bf16x8*)&pl[w][lane15 * 72 + nc * 32 + quad * 8];
        #pragma unroll
        for (int dt = 0; dt < 4; ++dt) {
          const int vrow = dt * 16 + lane15;
          bf16x8 bv = *(const bf16x8*)&vt[vrow * 64 + ((nc * 32 + quad * 8) ^ swx)];
          O[qh][dt] = __builtin_amdgcn_mfma_f32_16x16x32_bf16(ap, bv, O[qh][dt], 0, 0, 0);
        }
      }
      __builtin_amdgcn_s_setprio(0);
    }
  }

  #pragma unroll
  for (int qh = 0; qh < 2; ++qh) {
    float s = lsum[qh];
    s += __shfl_xor(s, 16);
    s += __shfl_xor(s, 32);
    float inv = 1.f / s;
    float invr[4], lfr[4], hfr[4];
    const size_t rowb = (size_t)(b * N_ + q0 + w * 32 + qh * 16 + quad * 4);
    #pragma unroll
    for (int r = 0; r < 4; ++r) {
      invr[r] = __shfl(inv, quad * 4 + r);
      lfr[r] = lf[(rowb + r) * 8 + h];
      hfr[r] = hf[(rowb + r) * 8 + h];
    }
    #pragma unroll
    for (int dt = 0; dt < 4; ++dt) {
      const int cc = h * 64 + dt * 16 + lane15;
      const float lg = lgam[cc], hg = hgam[cc];
      #pragma unroll
      for (int r = 0; r < 4; ++r) {
        float a = O[qh][dt][r] * invr[r];
        float vval = bf2f(qkv[(rowb + r) * C3_ + 1024 + cc]);
        float res = a + a * lfr[r] * lg + hfr[r] * (vval - a) * hg;
        y[(rowb + r) * C_ + cc] = f2bf(res);
      }
    }
  }
}

// ---------------- routing: pooled(B,C) -> routing(B,64) ----------------
__global__ __launch_bounds__(256) void k_routing(const float* __restrict__ pooled,
    const float* __restrict__ rw1, const float* __restrict__ rw1s,
    const float* __restrict__ rw1b, const float* __restrict__ rw2,
    float* __restrict__ routing) {
  const int b = blockIdx.x, t = threadIdx.x;
  __shared__ float plds[512];
  __shared__ float tile[64][65];
  __shared__ float hl[64];
  plds[t] = pooled[b * 512 + t];
  plds[t + 256] = pooled[b * 512 + t + 256];
  __syncthreads();
  float acc = 0.f;
  for (int c0 = 0; c0 < 512; c0 += 64) {
    #pragma unroll
    for (int kk = 0; kk < 16; ++kk) {
      int idx = kk * 256 + t;
      tile[idx >> 6][idx & 63] = rw1[(size_t)(idx >> 6) * 512 + c0 + (idx & 63)];
    }
    __syncthreads();
    if (t < 64) {
      #pragma unroll
      for (int i = 0; i < 64; ++i) acc += plds[c0 + i] * tile[t][i];
    }
    __syncthreads();
  }
  if (t < 64) {
    float r = fmaxf(acc, 0.f);
    hl[t] = rw1s[0] * r * r + rw1b[0];
  }
  __syncthreads();
  if (t < 64) {
    float r2 = 0.f;
    #pragma unroll
    for (int j = 0; j < 64; ++j) r2 += hl[j] * rw2[(size_t)t * 64 + j];
    routing[b * 64 + t] = tanhf(r2);
  }
}

// ---------------- per-plane 32x32 rfft2 * dyn -> irfft2 via MFMA, fused residual ------
// feat is now bf16 (B,C,N); res/out remain f32.
__global__ __launch_bounds__(256) void k_freq(const unsigned short* __restrict__ feat,
    const float* __restrict__ routing, const float* __restrict__ fwtab,
    const unsigned short* __restrict__ gtab, const float* __restrict__ res,
    const float* __restrict__ gamma, float* __restrict__ outp) {
  const int c = blockIdx.x, b = blockIdx.y, t = threadIdx.x;
  const int g = c >> 5, cc = c & 31;
  const int w = t >> 6, l = t & 63;
  const int lane15 = l & 15, quad = l >> 4;
  const int mt = w & 1, nt = w >> 1;
  __shared__ __align__(16) unsigned short Xbf[32 * 40];
  __shared__ __align__(16) float p[32 * 36];
  __shared__ __align__(16) unsigned short Tabs[6400];
  __shared__ __align__(16) unsigned short pl1r[32 * 40], pl1i[32 * 40];
  __shared__ __align__(16) unsigned short pl2r[32 * 40], pl2i[32 * 40];
  __shared__ __align__(16) unsigned short pl3r[32 * 40], pl3i[32 * 40];
  __shared__ float Ms[1024];
  const size_t base = (size_t)(b * C_ + c) * N_;

  {
    u16x4 xb = *(const u16x4*)&feat[base + t * 4];
    float4 v = make_float4(bf2f(xb[0]), bf2f(xb[1]), bf2f(xb[2]), bf2f(xb[3]));
    int hh = t >> 3, w4 = (t & 7) * 4;
    *(float4*)&p[hh * 36 + w4] = v;
    *(u16x4*)&Xbf[hh * 40 + w4] = xb;
  }
  {
    const uint4* src = (const uint4*)gtab;
    uint4* dst = (uint4*)Tabs;
    #pragma unroll
    for (int k = 0; k < 4; ++k) {
      int o = k * 256 + t;
      if (o < 800) dst[o] = src[o];
    }
  }
  {
    float r0 = routing[b * 64 + g * 4 + 0];
    float r1 = routing[b * 64 + g * 4 + 1];
    float r2 = routing[b * 64 + g * 4 + 2];
    float r3 = routing[b * 64 + g * 4 + 3];
    const float* fb = fwtab + (size_t)cc * 544;
    #pragma unroll
    for (int k = 0; k < 4; ++k) {
      int o = k * 256 + t;
      int fh = o >> 5, fw = o & 31;
      float mv = 0.f;
      if (fw < 17) {
        int fi = fh * 17 + fw;
        mv = (r0 * fb[fi] + r1 * fb[17408 + fi] + r2 * fb[34816 + fi] +
              r3 * fb[52224 + fi]) * (1.f / 1024.f);
      }
      Ms[o] = mv;
    }
  }
  __syncthreads();

  const unsigned short* Tc  = Tabs;
  const unsigned short* Ts  = Tabs + 1280;
  const unsigned short* Tsn = Tabs + 2560;
  const unsigned short* Tcw = Tabs + 3840;
  const unsigned short* Tsw = Tabs + 5120;
  const int arow = (mt * 16 + lane15) * 40 + quad * 8;
  const int brow = (nt * 16 + lane15) * 40 + quad * 8;
  const int prow = (nt * 16 + lane15) * 40 + mt * 16 + quad * 4;
  const f32x4 zz = (f32x4){0.f, 0.f, 0.f, 0.f};

  {
    bf16x8 aX = *(const bf16x8*)&Xbf[arow];
    bf16x8 bC = *(const bf16x8*)&Tc[brow];
    bf16x8 bS = *(const bf16x8*)&Tsn[brow];
    f32x4 re = __builtin_amdgcn_mfma_f32_16x16x32_bf16(aX, bC, zz, 0, 0, 0);
    f32x4 im = __builtin_amdgcn_mfma_f32_16x16x32_bf16(aX, bS, zz, 0, 0, 0);
    uint2 pr = make_uint2(__builtin_amdgcn_perm(f2u(re[1]), f2u(re[0]), 0x07060302u),
                          __builtin_amdgcn_perm(f2u(re[3]), f2u(re[2]), 0x07060302u));
    uint2 pi = make_uint2(__builtin_amdgcn_perm(f2u(im[1]), f2u(im[0]), 0x07060302u),
                          __builtin_amdgcn_perm(f2u(im[3]), f2u(im[2]), 0x07060302u));
    *(uint2*)&pl1r[prow] = pr;
    *(uint2*)&pl1i[prow] = pi;
  }
  __syncthreads();
  {
    bf16x8 aC = *(const bf16x8*)&Tc[arow];
    bf16x8 aS = *(const bf16x8*)&Ts[arow];
    bf16x8 aN = *(const bf16x8*)&Tsn[arow];
    bf16x8 bR = *(const bf16x8*)&pl1r[brow];
    bf16x8 bI = *(const bf16x8*)&pl1i[brow];
    f32x4 er = __builtin_amdgcn_mfma_f32_16x16x32_bf16(aC, bR, zz, 0, 0, 0);
    er = __builtin_amdgcn_mfma_f32_16x16x32_bf16(aS, bI, er, 0, 0, 0);
    f32x4 ei = __builtin_amdgcn_mfma_f32_16x16x32_bf16(aC, bI, zz, 0, 0, 0);
    ei = __builtin_amdgcn_mfma_f32_16x16x32_bf16(aN, bR, ei, 0, 0, 0);
    #pragma unroll
    for (int r = 0; r < 4; ++r) {
      float mk = Ms[(mt * 16 + quad * 4 + r) * 32 + nt * 16 + lane15];
      er[r] *= mk; ei[r] *= mk;
    }
    uint2 pr = make_uint2(__builtin_amdgcn_perm(f2u(er[1]), f2u(er[0]), 0x07060302u),
                          __builtin_amdgcn_perm(f2u(er[3]), f2u(er[2]), 0x07060302u));
    uint2 pi = make_uint2(__builtin_amdgcn_perm(f2u(ei[1]), f2u(ei[0]), 0x07060302u),
                          __builtin_amdgcn_perm(f2u(ei[3]), f2u(ei[2]), 0x07060302u));
    *(uint2*)&pl2r[prow] = pr;
    *(uint2*)&pl2i[prow] = pi;
  }
  __syncthreads();
  {
    bf16x8 aR = *(const bf16x8*)&pl2r[arow];
    bf16x8 aI = *(const bf16x8*)&pl2i[arow];
    bf16x8 bC = *(const bf16x8*)&Tc[brow];
    bf16x8 bS = *(const bf16x8*)&Ts[brow];
    bf16x8 bN = *(const bf16x8*)&Tsn[brow];
    f32x4 zr = __builtin_amdgcn_mfma_f32_16x16x32_bf16(aR, bC, zz, 0, 0, 0);
    zr = __builtin_amdgcn_mfma_f32_16x16x32_bf16(aI, bN, zr, 0, 0, 0);
    f32x4 zi = __builtin_amdgcn_mfma_f32_16x16x32_bf16(aI, bC, zz, 0, 0, 0);
    zi = __builtin_amdgcn_mfma_f32_16x16x32_bf16(aR, bS, zi, 0, 0, 0);
    uint2 pr = make_uint2(__builtin_amdgcn_perm(f2u(zr[1]), f2u(zr[0]), 0x07060302u),
                          __builtin_amdgcn_perm(f2u(zr[3]), f2u(zr[2]), 0x07060302u));
    uint2 pi = make_uint2(__builtin_amdgcn_perm(f2u(zi[1]), f2u(zi[0]), 0x07060302u),
                          __builtin_amdgcn_perm(f2u(zi[3]), f2u(zi[2]), 0x07060302u));
    *(uint2*)&pl3r[prow] = pr;
    *(uint2*)&pl3i[prow] = pi;
  }
  __syncthreads();
  {
    bf16x8 aC = *(const bf16x8*)&Tcw[arow];
    bf16x8 aS = *(const bf16x8*)&Tsw[arow];
    bf16x8 bR = *(const bf16x8*)&pl3r[brow];
    bf16x8 bI = *(const bf16x8*)&pl3i[brow];
    f32x4 y = __builtin_amdgcn_mfma_f32_16x16x32_bf16(aC, bR, zz, 0, 0, 0);
    y = __builtin_amdgcn_mfma_f32_16x16x32_bf16(aS, bI, y, 0, 0, 0);
    int hh = nt * 16 + lane15, w0 = mt * 16 + quad * 4;
    float4 fp = *(const float4*)&p[hh * 36 + w0];
    float4 rp = *(const float4*)&res[base + hh * 32 + w0];
    float gv = gamma[c];
    float4 o = make_float4(rp.x + gv * (y[0] + fp.x), rp.y + gv * (y[1] + fp.y),
                           rp.z + gv * (y[2] + fp.z), rp.w + gv * (y[3] + fp.w));
    *(float4*)&outp[base + hh * 32 + w0] = o;
  }
}

// =============================== launch ===============================
extern "C" void kernel_launch(void* const* d_in, const int* in_sizes, int n_in,
                              void* d_out, int out_size, void* d_ws, size_t ws_size,
                              hipStream_t stream) {
  (void)in_sizes; (void)n_in; (void)out_size; (void)ws_size;
  const float* x      = (const float*)d_in[0];
  const float* n1w    = (const float*)d_in[1];
  const float* n1b    = (const float*)d_in[2];
  const float* qkv_w  = (const float*)d_in[3];
  const float* proj_w = (const float*)d_in[4];
  const float* proj_b = (const float*)d_in[5];
  const float* pa_s   = (const float*)d_in[6];
  const float* pa_b   = (const float*)d_in[7];
  const float* lf_w   = (const float*)d_in[8];
  const float* lf_b   = (const float*)d_in[9];
  const float* hf_w   = (const float*)d_in[10];
  const float* hf_b   = (const float*)d_in[11];
  const float* lf_g   = (const float*)d_in[12];
  const float* hf_g   = (const float*)d_in[13];
  const float* f1rw1w = (const float*)d_in[14];
  const float* f1rw1s = (const float*)d_in[15];
  const float* f1rw1b = (const float*)d_in[16];
  const float* f1rw2w = (const float*)d_in[17];
  const float* f1fw   = (const float*)d_in[18];
  const float* gamma1 = (const float*)d_in[19];
  const float* n2w    = (const float*)d_in[20];
  const float* n2b    = (const float*)d_in[21];
  const float* fc1w   = (const float*)d_in[22];
  const float* fc1b   = (const float*)d_in[23];
  const float* fc2w   = (const float*)d_in[24];
  const float* fc2b   = (const float*)d_in[25];
  const float* f2rw1w = (const float*)d_in[26];
  const float* f2rw1s = (const float*)d_in[27];
  const float* f2rw1b = (const float*)d_in[28];
  const float* f2rw2w = (const float*)d_in[29];
  const float* f2fw   = (const float*)d_in[30];
  const float* gamma2 = (const float*)d_in[31];

  char* ws = (char*)d_ws;
  float*          tokens = (float*)(ws + 0);              // tokens_f1 (B,C,N) f32
  float*          f1buf  = (float*)(ws + 33554432ULL);
  unsigned short* featb  = (unsigned short*)(ws + 67108864ULL);  // feat (B,C,N) bf16
  unsigned short* regA   = (unsigned short*)(ws + 134217728ULL);
  unsigned short* abuf   = (unsigned short*)(ws + 201326592ULL);
  float*          lfbuf  = (float*)(ws + 218103808ULL);
  float*          hfbuf  = (float*)(ws + 218628096ULL);
  float*          pooled = (float*)(ws + 219152384ULL);
  float*          routing= (float*)(ws + 219185152ULL);
  unsigned short* wq     = (unsigned short*)(ws + 219189248ULL);
  unsigned short* wp     = (unsigned short*)(ws + 220762112ULL);
  unsigned short* w1     = (unsigned short*)(ws + 221286400ULL);
  unsigned short* w2     = (unsigned short*)(ws + 223383552ULL);
  unsigned short* gtab   = (unsigned short*)(ws + 225480704ULL);
  unsigned short* vtg    = (unsigned short*)f1buf;
  float*          pooled2= (float*)(ws + 50331648ULL);    // spare half of f1buf window

  k_f2b4<<<12288, 256, 0, stream>>>(qkv_w, wq, proj_w, wp, fc1w, w1, fc2w, w2);
  k_twid<<<89, 256, 0, stream>>>(gtab, pooled, pooled2);

  // LN1 fused with transpose (reads x in B,C,N) + gates
  k_lnt<true><<<dim3(32, 16), 256, 0, stream>>>(x, n1w, n1b, lf_w, lf_b, hf_w, hf_b,
                                                pa_s, pa_b, abuf, lfbuf, hfbuf);
  // GEMMs on XCD-chunked 1D grids (nwg multiple of 8)
  k_gemm<0><<<1536, 256, 0, stream>>>(abuf, wq, n1b, regA, vtg, C3_, C_, 12);
  k_flash<<<1024, 256, 0, stream>>>(regA, vtg, lfbuf, hfbuf, lf_g, hf_g, abuf);
  k_gemm<1><<<512, 256, 0, stream>>>(abuf, wp, proj_b, featb,
                                     (unsigned short*)pooled, C_, C_, 4);
  k_routing<<<16, 256, 0, stream>>>(pooled, f1rw1w, f1rw1s, f1rw1b, f1rw2w, routing);
  // freq1 + fused residual: tokens = x + gamma1*(dft + feat)
  k_freq<<<dim3(512, 16), 256, 0, stream>>>(featb, routing, f1fw, gtab, x, gamma1, tokens);
  // LN2 fused with transpose (reads tokens in B,C,N)
  k_lnt<false><<<dim3(32, 16), 256, 0, stream>>>(tokens, n2w, n2b, nullptr, nullptr,
                                                 nullptr, nullptr, nullptr, nullptr,
                                                 abuf, nullptr, nullptr);
  k_gemm<2><<<2048, 256, 0, stream>>>(abuf, w1, fc1b, regA, nullptr, CH_, C_, 16);
  k_gemm<3><<<512, 256, 0, stream>>>(regA, w2, fc2b, featb,
                                     (unsigned short*)pooled2, C_, CH_, 4);
  k_routing<<<16, 256, 0, stream>>>(pooled2, f2rw1w, f2rw1s, f2rw1b, f2rw2w, routing);
  // freq2 + fused residual: out = tokens + gamma2*(dft + feat)
  k_freq<<<dim3(512, 16), 256, 0, stream>>>(featb, routing, f2fw, gtab, tokens, gamma2,
                                            (float*)d_out);
}

// Round 4
// 477.474 us; speedup vs baseline: 1.0872x; 1.0206x over previous
//
#include <hip/hip_runtime.h>
#include <cstdint>
#include <cstddef>

#define B_   16
#define C_   512
#define N_   1024
#define M_   (B_*N_)
#define NH_  8
#define HD_  64
#define C3_  1536
#define CH_  2048

typedef __attribute__((ext_vector_type(8))) short bf16x8;
typedef __attribute__((ext_vector_type(4))) float f32x4;
typedef __attribute__((ext_vector_type(4))) unsigned short u16x4;

__device__ __forceinline__ unsigned short f2bf(float f) {
  union { float f; unsigned u; } v; v.f = f;
  unsigned r = v.u + 0x7fffu + ((v.u >> 16) & 1u);
  return (unsigned short)(r >> 16);
}
__device__ __forceinline__ float bf2f(unsigned short h) {
  union { unsigned u; float f; } v; v.u = ((unsigned)h) << 16;
  return v.f;
}
__device__ __forceinline__ unsigned f2u(float f) {
  union { float f; unsigned u; } v; v.f = f; return v.u;
}

// global -> LDS direct DMA, 16B per lane. LDS dest is wave-uniform base +
// lane*16 (linear); swizzled layouts via pre-swizzled GLOBAL source (m173).
#define GL16(gp, lp) \
  __builtin_amdgcn_global_load_lds( \
      (const __attribute__((address_space(1))) unsigned int*)(const void*)(gp), \
      (__attribute__((address_space(3))) unsigned int*)(void*)(lp), 16, 0, 0)

// ---------------- fused float -> bf16 conversion for all 4 weight mats ----------------
__global__ __launch_bounds__(256) void k_f2b4(
    const float* __restrict__ s0, unsigned short* __restrict__ d0,
    const float* __restrict__ s1, unsigned short* __restrict__ d1,
    const float* __restrict__ s2, unsigned short* __restrict__ d2,
    const float* __restrict__ s3, unsigned short* __restrict__ d3) {
  int blk = blockIdx.x, t = threadIdx.x;
  const float* s; unsigned short* d; int off;
  if (blk < 3072)      { s = s0; d = d0; off = blk * 256; }
  else if (blk < 4096) { s = s1; d = d1; off = (blk - 3072) * 256; }
  else if (blk < 8192) { s = s2; d = d2; off = (blk - 4096) * 256; }
  else                 { s = s3; d = d3; off = (blk - 8192) * 256; }
  int i = off + t;
  d[i] = f2bf(s[i]);
}

// ---------------- twiddle tables + zero the two pooled accumulators ----------------
__global__ __launch_bounds__(256) void k_twid(unsigned short* __restrict__ gtab,
                                              float* __restrict__ p1,
                                              float* __restrict__ p2) {
  int idx = blockIdx.x * 256 + threadIdx.x;
  if (idx < 6400) {
    int tab = idx / 1280, rem = idx % 1280;
    int i = rem / 40, j = rem % 40;
    float v = 0.f;
    if (j < 32) {
      float th = 0.19634954084936207f * (float)((i * j) & 31);
      float s, c;
      __sincosf(th, &s, &c);
      if (tab == 0) v = c;
      else if (tab == 1) v = s;
      else if (tab == 2) v = -s;
      else {
        float wg = (j == 0 || j == 16) ? 1.f : 2.f;
        if (j >= 17) wg = 0.f;
        v = (tab == 3) ? wg * c : -wg * s;
      }
    }
    gtab[idx] = f2bf(v);
  } else if (idx < 14592) {
    p1[idx - 6400] = 0.f;
  } else if (idx < 22784) {
    p2[idx - 14592] = 0.f;
  }
}

// ---------------- fused transpose + LayerNorm (+ optional lf/hf gates) ----------------
template<bool WITH>
__global__ __launch_bounds__(256) void k_lnt(const float* __restrict__ src,
    const float* __restrict__ w, const float* __restrict__ bia,
    const float* __restrict__ lfw, const float* __restrict__ lfb,
    const float* __restrict__ hfw, const float* __restrict__ hfb,
    const float* __restrict__ pa_s, const float* __restrict__ pa_b,
    unsigned short* __restrict__ lnout, float* __restrict__ lfout,
    float* __restrict__ hfout) {
  __shared__ unsigned short s[512 * 34];
  const int t = threadIdx.x, wv = t >> 6, l = t & 63;
  const int n0 = blockIdx.x * 32, b = blockIdx.y;
  const int cl = t >> 3;
  const int nn = (t & 7) * 4;
  #pragma unroll
  for (int k = 0; k < 16; ++k) {
    int c = k * 32 + cl;
    float4 v = *(const float4*)&src[(size_t)(b * C_ + c) * N_ + n0 + nn];
    s[c * 34 + nn]     = f2bf(v.x);
    s[c * 34 + nn + 1] = f2bf(v.y);
    s[c * 34 + nn + 2] = f2bf(v.z);
    s[c * 34 + nn + 3] = f2bf(v.w);
  }
  __syncthreads();
  float wv8[8], bv8[8];
  #pragma unroll
  for (int k = 0; k < 8; ++k) { wv8[k] = w[l + 64 * k]; bv8[k] = bia[l + 64 * k]; }
  float ps = 1.f, pb = 0.f;
  if (WITH) { ps = pa_s[0]; pb = pa_b[0]; }
  for (int ri = 0; ri < 8; ++ri) {
    const int n = wv * 8 + ri;
    const int row = b * N_ + n0 + n;
    float v[8];
    #pragma unroll
    for (int k = 0; k < 8; ++k) v[k] = bf2f(s[(l + 64 * k) * 34 + n]);
    float sm = 0.f, q = 0.f;
    #pragma unroll
    for (int k = 0; k < 8; ++k) { sm += v[k]; q += v[k] * v[k]; }
    #pragma unroll
    for (int off = 1; off < 64; off <<= 1) { sm += __shfl_xor(sm, off); q += __shfl_xor(q, off); }
    float mu = sm * (1.f / 512.f);
    float var = q * (1.f / 512.f) - mu * mu;
    float rstd = rsqrtf(var + 1e-5f);
    float ln[8];
    #pragma unroll
    for (int k = 0; k < 8; ++k) ln[k] = (v[k] - mu) * rstd * wv8[k] + bv8[k];
    #pragma unroll
    for (int k = 0; k < 8; ++k)
      lnout[(size_t)row * C_ + l + 64 * k] = f2bf(ln[k]);
    if (WITH) {
      float d[8];
      #pragma unroll
      for (int k = 0; k < 8; ++k) { float r = fmaxf(ln[k], 0.f); d[k] = ps * r * r + pb; }
      float lacc[8], hacc[8];
      #pragma unroll
      for (int h = 0; h < 8; ++h) {
        float la = 0.f, ha = 0.f;
        #pragma unroll
        for (int k = 0; k < 8; ++k) {
          la += d[k] * lfw[h * C_ + l + 64 * k];
          ha += d[k] * hfw[h * C_ + l + 64 * k];
        }
        lacc[h] = la; hacc[h] = ha;
      }
      #pragma unroll
      for (int h = 0; h < 8; ++h)
        #pragma unroll
        for (int off = 1; off < 64; off <<= 1) {
          lacc[h] += __shfl_xor(lacc[h], off);
          hacc[h] += __shfl_xor(hacc[h], off);
        }
      float lv = lacc[0], hv = hacc[0];
      #pragma unroll
      for (int h = 1; h < 8; ++h) { if (l == h) { lv = lacc[h]; hv = hacc[h]; } }
      if (l < 8) {
        lfout[(size_t)row * 8 + l] = tanhf(lv + lfb[l]);
        float z = hv + hfb[l];
        float sp = (z > 15.f) ? z : log1pf(__expf(z));
        float s2 = sp * sp;
        hfout[(size_t)row * 8 + l] = 2.f * s2 / (s2 + 0.3678f);
      }
    }
  }
}

// ---------------- GEMM v4: double-buffered global_load_lds prefetch pipeline ----------
// 128x128 tile, BK=32. Per K-step: stage(next) -> compute(cur) -> barrier.
// EPI 1/3 write bf16 feat + accumulate the spatial mean pool (vtg = pooled f32).
template<int EPI>
__global__ __launch_bounds__(256) void k_gemm(const unsigned short* __restrict__ A,
    const unsigned short* __restrict__ Bt, const float* __restrict__ bias,
    void* __restrict__ outv, unsigned short* __restrict__ vtg, int Nn, int K, int nx) {
  __shared__ __align__(16) unsigned short Asm[2 * 128 * 32];
  __shared__ __align__(16) unsigned short Bsm[2 * 128 * 32];
  const int t = threadIdx.x, w = t >> 6, l = t & 63;
  const int lane15 = l & 15, quad = l >> 4;
  const int cpx = gridDim.x >> 3;
  const int wgs = (blockIdx.x & 7) * cpx + (blockIdx.x >> 3);
  const int bx = wgs % nx, by = wgs / nx;
  const int n0 = bx * 128, m0 = by * 128;
  const int wm = w >> 1, wn = w & 1;
  f32x4 acc[4][4];
  #pragma unroll
  for (int i = 0; i < 4; ++i)
    #pragma unroll
    for (int j = 0; j < 4; ++j) acc[i][j] = (f32x4){0.f, 0.f, 0.f, 0.f};
  const int srow = w * 16 + (l >> 2);
  const int scol = (l & 3) * 8;
  const unsigned short* gA = A + (size_t)(m0 + srow) * K + scol;
  const unsigned short* gB = Bt + (size_t)(n0 + srow) * K + scol;
  const size_t rk64 = (size_t)64 * K;
  auto stage = [&](int bufi, int k0) {
    char* a = (char*)Asm + bufi * 8192 + w * 1024;
    char* bb = (char*)Bsm + bufi * 8192 + w * 1024;
    GL16(gA + k0, a);
    GL16(gA + k0 + rk64, a + 4096);
    GL16(gB + k0, bb);
    GL16(gB + k0 + rk64, bb + 4096);
  };
  stage(0, 0);
  __syncthreads();
  for (int k0 = 0; k0 < K; k0 += 32) {
    const int cur = (k0 >> 5) & 1;
    if (k0 + 32 < K) stage(cur ^ 1, k0 + 32);
    const unsigned short* As = Asm + cur * 4096;
    const unsigned short* Bs = Bsm + cur * 4096;
    bf16x8 af[4], bg[4];
    #pragma unroll
    for (int i = 0; i < 4; ++i)
      af[i] = *(const bf16x8*)&As[(wm * 64 + i * 16 + lane15) * 32 + quad * 8];
    #pragma unroll
    for (int i = 0; i < 4; ++i)
      bg[i] = *(const bf16x8*)&Bs[(wn * 64 + i * 16 + lane15) * 32 + quad * 8];
    #pragma unroll
    for (int i = 0; i < 4; ++i)
      #pragma unroll
      for (int j = 0; j < 4; ++j)
        acc[i][j] = __builtin_amdgcn_mfma_f32_16x16x32_bf16(af[i], bg[j], acc[i][j], 0, 0, 0);
    __syncthreads();
  }
  float psum[4] = {0.f, 0.f, 0.f, 0.f};
  #pragma unroll
  for (int i = 0; i < 4; ++i) {
    int grow = m0 + wm * 64 + i * 16 + quad * 4;
    int bq = grow >> 10, nq = grow & 1023;
    #pragma unroll
    for (int j = 0; j < 4; ++j) {
      int gcol = n0 + wn * 64 + j * 16 + lane15;
      float bs = (EPI == 0) ? 0.f : bias[gcol];
      if (EPI == 1 || EPI == 3) {
        float4 o = make_float4(acc[i][j][0] + bs, acc[i][j][1] + bs,
                               acc[i][j][2] + bs, acc[i][j][3] + bs);
        psum[j] += o.x + o.y + o.z + o.w;
        u16x4 pv = { f2bf(o.x), f2bf(o.y), f2bf(o.z), f2bf(o.w) };
        *(u16x4*)&((unsigned short*)outv)[((size_t)(bq * C_ + gcol) << 10) + nq] = pv;
      } else if (EPI == 0) {
        u16x4 pv;
        #pragma unroll
        for (int r = 0; r < 4; ++r) {
          unsigned short hv = f2bf(acc[i][j][r]);
          pv[r] = hv;
          ((unsigned short*)outv)[(size_t)(grow + r) * Nn + gcol] = hv;
        }
        if (gcol >= 1024)
          *(u16x4*)&vtg[((size_t)(bq * C_ + gcol - 1024) << 10) + nq] = pv;
      } else {
        #pragma unroll
        for (int r = 0; r < 4; ++r) {
          float vv = acc[i][j][r] + bs;
          float e = __builtin_amdgcn_exp2f(-(2.302118073f * vv +
                                             0.1029455568f * vv * vv * vv));
          float g = vv * __builtin_amdgcn_rcpf(1.f + e);
          ((unsigned short*)outv)[(size_t)(grow + r) * Nn + gcol] = f2bf(g);
        }
      }
    }
  }
  if (EPI == 1 || EPI == 3) {
    float* pooled = (float*)vtg;
    const int bq = m0 >> 10;
    #pragma unroll
    for (int j = 0; j < 4; ++j) {
      float v = psum[j] * (1.f / 1024.f);
      v += __shfl_xor(v, 16);
      v += __shfl_xor(v, 32);
      if (quad == 0) {
        int gcol = n0 + wn * 64 + j * 16 + lane15;
        atomicAdd(&pooled[bq * C_ + gcol], v);
      }
    }
  }
}

// ---------------- flash attention v8: 256 q rows/block, drain amortized 2x ----------
// Single-buffered 64-row K/V tiles (drain-then-compute, the verified structure);
// each drain now covers 4 qh sub-tiles of compute instead of 2. Grid 512,
// XCD-chunked; >=2 blocks/CU resident.
__global__ __launch_bounds__(256, 2) void k_flash(const unsigned short* __restrict__ qkv,
    const unsigned short* __restrict__ vtg, const float* __restrict__ lf,
    const float* __restrict__ hf, const float* __restrict__ lgam,
    const float* __restrict__ hgam, unsigned short* __restrict__ y) {
  const int t = threadIdx.x, w = t >> 6, l = t & 63;
  const int lane15 = l & 15, quad = l >> 4;
  const int wg = (blockIdx.x & 7) * 64 + (blockIdx.x >> 3);   // XCD chunking
  const int qt = wg & 3;
  const int h = (wg >> 2) & 7;
  const int b = wg >> 5;
  const int q0 = qt * 256;

  __shared__ __align__(16) unsigned short kt[64 * 64];   // [n][d], stride 64, XOR-swz
  __shared__ __align__(16) unsigned short vt[64 * 64];   // [d][n], stride 64, XOR-swz
  __shared__ __align__(16) unsigned short pl[4][16 * 72];

  // Q fragments: wave w owns q rows q0 + w*64 + qh*16 + lane15, qh in 0..3
  bf16x8 aq[4][2];
  #pragma unroll
  for (int qh = 0; qh < 4; ++qh) {
    const unsigned short* qp = qkv +
        (size_t)(b * N_ + q0 + w * 64 + qh * 16 + lane15) * C3_ + h * 64 + quad * 8;
    bf16x8 r0 = *(const bf16x8*)qp;
    bf16x8 r1 = *(const bf16x8*)(qp + 32);
    #pragma unroll
    for (int i = 0; i < 8; ++i) {
      aq[qh][0][i] = (short)f2bf(0.1803368801111713f * bf2f((unsigned short)r0[i]));
      aq[qh][1][i] = (short)f2bf(0.1803368801111713f * bf2f((unsigned short)r1[i]));
    }
  }
  f32x4 O[4][4];
  #pragma unroll
  for (int qh = 0; qh < 4; ++qh)
    #pragma unroll
    for (int i = 0; i < 4; ++i) O[qh][i] = (f32x4){0.f, 0.f, 0.f, 0.f};
  float lsum[4] = {0.f, 0.f, 0.f, 0.f};

  // staging: lane covers phys row w*8+(l>>3), phys col (l&7)*16B; logical col
  // = phys ^ ((row&7)<<4); row&7 == l>>3 -> pre-swizzle the global source.
  const int prow = w * 8 + (l >> 3);
  const int csw = ((l & 7) ^ (l >> 3)) * 8;
  const unsigned short* kg = qkv + (size_t)(b * N_ + prow) * C3_ + 512 + h * 64 + csw;
  const unsigned short* vg = vtg + (size_t)((b * NH_ + h) * HD_ + prow) * N_ + csw;
  char* ktb0 = (char*)kt + w * 1024;
  char* ktb1 = (char*)kt + 4096 + w * 1024;
  char* vtb0 = (char*)vt + w * 1024;
  char* vtb1 = (char*)vt + 4096 + w * 1024;
  const int swx = (lane15 & 7) * 8;                       // read-side XOR (shorts)

  for (int kti = 0; kti < 16; ++kti) {
    __syncthreads();
    const unsigned short* kr = kg + (size_t)(kti * 64) * C3_;
    GL16(kr, ktb0);
    GL16(kr + (size_t)32 * C3_, ktb1);
    const unsigned short* vr = vg + kti * 64;
    GL16(vr, vtb0);
    GL16(vr + 32 * N_, vtb1);
    __syncthreads();                                      // tile ready

    #pragma unroll
    for (int qh = 0; qh < 4; ++qh) {
      f32x4 S[4];
      __builtin_amdgcn_s_setprio(1);
      #pragma unroll
      for (int nt = 0; nt < 4; ++nt) {
        const int nrow = nt * 16 + lane15;
        bf16x8 ak0 = *(const bf16x8*)&kt[nrow * 64 + ((quad * 8) ^ swx)];
        bf16x8 ak1 = *(const bf16x8*)&kt[nrow * 64 + ((32 + quad * 8) ^ swx)];
        f32x4 z = (f32x4){0.f, 0.f, 0.f, 0.f};
        z = __builtin_amdgcn_mfma_f32_16x16x32_bf16(ak0, aq[qh][0], z, 0, 0, 0);
        z = __builtin_amdgcn_mfma_f32_16x16x32_bf16(ak1, aq[qh][1], z, 0, 0, 0);
        S[nt] = z;
      }
      __builtin_amdgcn_s_setprio(0);
      #pragma unroll
      for (int nt = 0; nt < 4; ++nt)
        #pragma unroll
        for (int r = 0; r < 4; ++r) {
          float pv = __builtin_amdgcn_exp2f(S[nt][r]);
          S[nt][r] = pv;
          lsum[qh] += pv;
        }
      #pragma unroll
      for (int nt = 0; nt < 4; ++nt) {
        unsigned lo = __builtin_amdgcn_perm(f2u(S[nt][1]), f2u(S[nt][0]), 0x07060302u);
        unsigned hi = __builtin_amdgcn_perm(f2u(S[nt][3]), f2u(S[nt][2]), 0x07060302u);
        *(uint2*)&pl[w][lane15 * 72 + nt * 16 + quad * 4] = make_uint2(lo, hi);
      }
      __builtin_amdgcn_s_setprio(1);
      #pragma unroll
      for (int nc = 0; nc < 2; ++nc) {
        bf16x8 ap = *(const bf16x8*)&pl[w][lane15 * 72 + nc * 32 + quad * 8];
        #pragma unroll
        for (int dt = 0; dt < 4; ++dt) {
          const int vrow = dt * 16 + lane15;
          bf16x8 bv = *(const bf16x8*)&vt[vrow * 64 + ((nc * 32 + quad * 8) ^ swx)];
          O[qh][dt] = __builtin_amdgcn_mfma_f32_16x16x32_bf16(ap, bv, O[qh][dt], 0, 0, 0);
        }
      }
      __builtin_amdgcn_s_setprio(0);
    }
  }

  #pragma unroll
  for (int qh = 0; qh < 4; ++qh) {
    float s = lsum[qh];
    s += __shfl_xor(s, 16);
    s += __shfl_xor(s, 32);
    float inv = 1.f / s;
    float invr[4], lfr[4], hfr[4];
    const size_t rowb = (size_t)(b * N_ + q0 + w * 64 + qh * 16 + quad * 4);
    #pragma unroll
    for (int r = 0; r < 4; ++r) {
      invr[r] = __shfl(inv, quad * 4 + r);
      lfr[r] = lf[(rowb + r) * 8 + h];
      hfr[r] = hf[(rowb + r) * 8 + h];
    }
    #pragma unroll
    for (int dt = 0; dt < 4; ++dt) {
      const int cc = h * 64 + dt * 16 + lane15;
      const float lg = lgam[cc], hg = hgam[cc];
      #pragma unroll
      for (int r = 0; r < 4; ++r) {
        float a = O[qh][dt][r] * invr[r];
        float vval = bf2f(qkv[(rowb + r) * C3_ + 1024 + cc]);
        float res = a + a * lfr[r] * lg + hfr[r] * (vval - a) * hg;
        y[(rowb + r) * C_ + cc] = f2bf(res);
      }
    }
  }
}

// ---------------- routing: pooled(B,C) -> routing(B,64) ----------------
__global__ __launch_bounds__(256) void k_routing(const float* __restrict__ pooled,
    const float* __restrict__ rw1, const float* __restrict__ rw1s,
    const float* __restrict__ rw1b, const float* __restrict__ rw2,
    float* __restrict__ routing) {
  const int b = blockIdx.x, t = threadIdx.x;
  __shared__ float plds[512];
  __shared__ float tile[64][65];
  __shared__ float hl[64];
  plds[t] = pooled[b * 512 + t];
  plds[t + 256] = pooled[b * 512 + t + 256];
  __syncthreads();
  float acc = 0.f;
  for (int c0 = 0; c0 < 512; c0 += 64) {
    #pragma unroll
    for (int kk = 0; kk < 16; ++kk) {
      int idx = kk * 256 + t;
      tile[idx >> 6][idx & 63] = rw1[(size_t)(idx >> 6) * 512 + c0 + (idx & 63)];
    }
    __syncthreads();
    if (t < 64) {
      #pragma unroll
      for (int i = 0; i < 64; ++i) acc += plds[c0 + i] * tile[t][i];
    }
    __syncthreads();
  }
  if (t < 64) {
    float r = fmaxf(acc, 0.f);
    hl[t] = rw1s[0] * r * r + rw1b[0];
  }
  __syncthreads();
  if (t < 64) {
    float r2 = 0.f;
    #pragma unroll
    for (int j = 0; j < 64; ++j) r2 += hl[j] * rw2[(size_t)t * 64 + j];
    routing[b * 64 + t] = tanhf(r2);
  }
}

// ---------------- per-plane 32x32 rfft2 * dyn -> irfft2 via MFMA, fused residual ------
// feat is bf16 (B,C,N); res/out remain f32.
__global__ __launch_bounds__(256) void k_freq(const unsigned short* __restrict__ feat,
    const float* __restrict__ routing, const float* __restrict__ fwtab,
    const unsigned short* __restrict__ gtab, const float* __restrict__ res,
    const float* __restrict__ gamma, float* __restrict__ outp) {
  const int c = blockIdx.x, b = blockIdx.y, t = threadIdx.x;
  const int g = c >> 5, cc = c & 31;
  const int w = t >> 6, l = t & 63;
  const int lane15 = l & 15, quad = l >> 4;
  const int mt = w & 1, nt = w >> 1;
  __shared__ __align__(16) unsigned short Xbf[32 * 40];
  __shared__ __align__(16) float p[32 * 36];
  __shared__ __align__(16) unsigned short Tabs[6400];
  __shared__ __align__(16) unsigned short pl1r[32 * 40], pl1i[32 * 40];
  __shared__ __align__(16) unsigned short pl2r[32 * 40], pl2i[32 * 40];
  __shared__ __align__(16) unsigned short pl3r[32 * 40], pl3i[32 * 40];
  __shared__ float Ms[1024];
  const size_t base = (size_t)(b * C_ + c) * N_;

  {
    u16x4 xb = *(const u16x4*)&feat[base + t * 4];
    float4 v = make_float4(bf2f(xb[0]), bf2f(xb[1]), bf2f(xb[2]), bf2f(xb[3]));
    int hh = t >> 3, w4 = (t & 7) * 4;
    *(float4*)&p[hh * 36 + w4] = v;
    *(u16x4*)&Xbf[hh * 40 + w4] = xb;
  }
  {
    const uint4* src = (const uint4*)gtab;
    uint4* dst = (uint4*)Tabs;
    #pragma unroll
    for (int k = 0; k < 4; ++k) {
      int o = k * 256 + t;
      if (o < 800) dst[o] = src[o];
    }
  }
  {
    float r0 = routing[b * 64 + g * 4 + 0];
    float r1 = routing[b * 64 + g * 4 + 1];
    float r2 = routing[b * 64 + g * 4 + 2];
    float r3 = routing[b * 64 + g * 4 + 3];
    const float* fb = fwtab + (size_t)cc * 544;
    #pragma unroll
    for (int k = 0; k < 4; ++k) {
      int o = k * 256 + t;
      int fh = o >> 5, fw = o & 31;
      float mv = 0.f;
      if (fw < 17) {
        int fi = fh * 17 + fw;
        mv = (r0 * fb[fi] + r1 * fb[17408 + fi] + r2 * fb[34816 + fi] +
              r3 * fb[52224 + fi]) * (1.f / 1024.f);
      }
      Ms[o] = mv;
    }
  }
  __syncthreads();

  const unsigned short* Tc  = Tabs;
  const unsigned short* Ts  = Tabs + 1280;
  const unsigned short* Tsn = Tabs + 2560;
  const unsigned short* Tcw = Tabs + 3840;
  const unsigned short* Tsw = Tabs + 5120;
  const int arow = (mt * 16 + lane15) * 40 + quad * 8;
  const int brow = (nt * 16 + lane15) * 40 + quad * 8;
  const int prow = (nt * 16 + lane15) * 40 + mt * 16 + quad * 4;
  const f32x4 zz = (f32x4){0.f, 0.f, 0.f, 0.f};

  {
    bf16x8 aX = *(const bf16x8*)&Xbf[arow];
    bf16x8 bC = *(const bf16x8*)&Tc[brow];
    bf16x8 bS = *(const bf16x8*)&Tsn[brow];
    f32x4 re = __builtin_amdgcn_mfma_f32_16x16x32_bf16(aX, bC, zz, 0, 0, 0);
    f32x4 im = __builtin_amdgcn_mfma_f32_16x16x32_bf16(aX, bS, zz, 0, 0, 0);
    uint2 pr = make_uint2(__builtin_amdgcn_perm(f2u(re[1]), f2u(re[0]), 0x07060302u),
                          __builtin_amdgcn_perm(f2u(re[3]), f2u(re[2]), 0x07060302u));
    uint2 pi = make_uint2(__builtin_amdgcn_perm(f2u(im[1]), f2u(im[0]), 0x07060302u),
                          __builtin_amdgcn_perm(f2u(im[3]), f2u(im[2]), 0x07060302u));
    *(uint2*)&pl1r[prow] = pr;
    *(uint2*)&pl1i[prow] = pi;
  }
  __syncthreads();
  {
    bf16x8 aC = *(const bf16x8*)&Tc[arow];
    bf16x8 aS = *(const bf16x8*)&Ts[arow];
    bf16x8 aN = *(const bf16x8*)&Tsn[arow];
    bf16x8 bR = *(const bf16x8*)&pl1r[brow];
    bf16x8 bI = *(const bf16x8*)&pl1i[brow];
    f32x4 er = __builtin_amdgcn_mfma_f32_16x16x32_bf16(aC, bR, zz, 0, 0, 0);
    er = __builtin_amdgcn_mfma_f32_16x16x32_bf16(aS, bI, er, 0, 0, 0);
    f32x4 ei = __builtin_amdgcn_mfma_f32_16x16x32_bf16(aC, bI, zz, 0, 0, 0);
    ei = __builtin_amdgcn_mfma_f32_16x16x32_bf16(aN, bR, ei, 0, 0, 0);
    #pragma unroll
    for (int r = 0; r < 4; ++r) {
      float mk = Ms[(mt * 16 + quad * 4 + r) * 32 + nt * 16 + lane15];
      er[r] *= mk; ei[r] *= mk;
    }
    uint2 pr = make_uint2(__builtin_amdgcn_perm(f2u(er[1]), f2u(er[0]), 0x07060302u),
                          __builtin_amdgcn_perm(f2u(er[3]), f2u(er[2]), 0x07060302u));
    uint2 pi = make_uint2(__builtin_amdgcn_perm(f2u(ei[1]), f2u(ei[0]), 0x07060302u),
                          __builtin_amdgcn_perm(f2u(ei[3]), f2u(ei[2]), 0x07060302u));
    *(uint2*)&pl2r[prow] = pr;
    *(uint2*)&pl2i[prow] = pi;
  }
  __syncthreads();
  {
    bf16x8 aR = *(const bf16x8*)&pl2r[arow];
    bf16x8 aI = *(const bf16x8*)&pl2i[arow];
    bf16x8 bC = *(const bf16x8*)&Tc[brow];
    bf16x8 bS = *(const bf16x8*)&Ts[brow];
    bf16x8 bN = *(const bf16x8*)&Tsn[brow];
    f32x4 zr = __builtin_amdgcn_mfma_f32_16x16x32_bf16(aR, bC, zz, 0, 0, 0);
    zr = __builtin_amdgcn_mfma_f32_16x16x32_bf16(aI, bN, zr, 0, 0, 0);
    f32x4 zi = __builtin_amdgcn_mfma_f32_16x16x32_bf16(aI, bC, zz, 0, 0, 0);
    zi = __builtin_amdgcn_mfma_f32_16x16x32_bf16(aR, bS, zi, 0, 0, 0);
    uint2 pr = make_uint2(__builtin_amdgcn_perm(f2u(zr[1]), f2u(zr[0]), 0x07060302u),
                          __builtin_amdgcn_perm(f2u(zr[3]), f2u(zr[2]), 0x07060302u));
    uint2 pi = make_uint2(__builtin_amdgcn_perm(f2u(zi[1]), f2u(zi[0]), 0x07060302u),
                          __builtin_amdgcn_perm(f2u(zi[3]), f2u(zi[2]), 0x07060302u));
    *(uint2*)&pl3r[prow] = pr;
    *(uint2*)&pl3i[prow] = pi;
  }
  __syncthreads();
  {
    bf16x8 aC = *(const bf16x8*)&Tcw[arow];
    bf16x8 aS = *(const bf16x8*)&Tsw[arow];
    bf16x8 bR = *(const bf16x8*)&pl3r[brow];
    bf16x8 bI = *(const bf16x8*)&pl3i[brow];
    f32x4 y = __builtin_amdgcn_mfma_f32_16x16x32_bf16(aC, bR, zz, 0, 0, 0);
    y = __builtin_amdgcn_mfma_f32_16x16x32_bf16(aS, bI, y, 0, 0, 0);
    int hh = nt * 16 + lane15, w0 = mt * 16 + quad * 4;
    float4 fp = *(const float4*)&p[hh * 36 + w0];
    float4 rp = *(const float4*)&res[base + hh * 32 + w0];
    float gv = gamma[c];
    float4 o = make_float4(rp.x + gv * (y[0] + fp.x), rp.y + gv * (y[1] + fp.y),
                           rp.z + gv * (y[2] + fp.z), rp.w + gv * (y[3] + fp.w));
    *(float4*)&outp[base + hh * 32 + w0] = o;
  }
}

// =============================== launch ===============================
extern "C" void kernel_launch(void* const* d_in, const int* in_sizes, int n_in,
                              void* d_out, int out_size, void* d_ws, size_t ws_size,
                              hipStream_t stream) {
  (void)in_sizes; (void)n_in; (void)out_size; (void)ws_size;
  const float* x      = (const float*)d_in[0];
  const float* n1w    = (const float*)d_in[1];
  const float* n1b    = (const float*)d_in[2];
  const float* qkv_w  = (const float*)d_in[3];
  const float* proj_w = (const float*)d_in[4];
  const float* proj_b = (const float*)d_in[5];
  const float* pa_s   = (const float*)d_in[6];
  const float* pa_b   = (const float*)d_in[7];
  const float* lf_w   = (const float*)d_in[8];
  const float* lf_b   = (const float*)d_in[9];
  const float* hf_w   = (const float*)d_in[10];
  const float* hf_b   = (const float*)d_in[11];
  const float* lf_g   = (const float*)d_in[12];
  const float* hf_g   = (const float*)d_in[13];
  const float* f1rw1w = (const float*)d_in[14];
  const float* f1rw1s = (const float*)d_in[15];
  const float* f1rw1b = (const float*)d_in[16];
  const float* f1rw2w = (const float*)d_in[17];
  const float* f1fw   = (const float*)d_in[18];
  const float* gamma1 = (const float*)d_in[19];
  const float* n2w    = (const float*)d_in[20];
  const float* n2b    = (const float*)d_in[21];
  const float* fc1w   = (const float*)d_in[22];
  const float* fc1b   = (const float*)d_in[23];
  const float* fc2w   = (const float*)d_in[24];
  const float* fc2b   = (const float*)d_in[25];
  const float* f2rw1w = (const float*)d_in[26];
  const float* f2rw1s = (const float*)d_in[27];
  const float* f2rw1b = (const float*)d_in[28];
  const float* f2rw2w = (const float*)d_in[29];
  const float* f2fw   = (const float*)d_in[30];
  const float* gamma2 = (const float*)d_in[31];

  char* ws = (char*)d_ws;
  float*          tokens = (float*)(ws + 0);              // tokens_f1 (B,C,N) f32
  float*          f1buf  = (float*)(ws + 33554432ULL);
  unsigned short* featb  = (unsigned short*)(ws + 67108864ULL);  // feat (B,C,N) bf16
  unsigned short* regA   = (unsigned short*)(ws + 134217728ULL);
  unsigned short* abuf   = (unsigned short*)(ws + 201326592ULL);
  float*          lfbuf  = (float*)(ws + 218103808ULL);
  float*          hfbuf  = (float*)(ws + 218628096ULL);
  float*          pooled = (float*)(ws + 219152384ULL);
  float*          routing= (float*)(ws + 219185152ULL);
  unsigned short* wq     = (unsigned short*)(ws + 219189248ULL);
  unsigned short* wp     = (unsigned short*)(ws + 220762112ULL);
  unsigned short* w1     = (unsigned short*)(ws + 221286400ULL);
  unsigned short* w2     = (unsigned short*)(ws + 223383552ULL);
  unsigned short* gtab   = (unsigned short*)(ws + 225480704ULL);
  unsigned short* vtg    = (unsigned short*)f1buf;
  float*          pooled2= (float*)(ws + 50331648ULL);    // spare half of f1buf window

  k_f2b4<<<12288, 256, 0, stream>>>(qkv_w, wq, proj_w, wp, fc1w, w1, fc2w, w2);
  k_twid<<<89, 256, 0, stream>>>(gtab, pooled, pooled2);

  // LN1 fused with transpose (reads x in B,C,N) + gates
  k_lnt<true><<<dim3(32, 16), 256, 0, stream>>>(x, n1w, n1b, lf_w, lf_b, hf_w, hf_b,
                                                pa_s, pa_b, abuf, lfbuf, hfbuf);
  // GEMMs on XCD-chunked 1D grids (nwg multiple of 8)
  k_gemm<0><<<1536, 256, 0, stream>>>(abuf, wq, n1b, regA, vtg, C3_, C_, 12);
  k_flash<<<512, 256, 0, stream>>>(regA, vtg, lfbuf, hfbuf, lf_g, hf_g, abuf);
  k_gemm<1><<<512, 256, 0, stream>>>(abuf, wp, proj_b, featb,
                                     (unsigned short*)pooled, C_, C_, 4);
  k_routing<<<16, 256, 0, stream>>>(pooled, f1rw1w, f1rw1s, f1rw1b, f1rw2w, routing);
  // freq1 + fused residual: tokens = x + gamma1*(dft + feat)
  k_freq<<<dim3(512, 16), 256, 0, stream>>>(featb, routing, f1fw, gtab, x, gamma1, tokens);
  // LN2 fused with transpose (reads tokens in B,C,N)
  k_lnt<false><<<dim3(32, 16), 256, 0, stream>>>(tokens, n2w, n2b, nullptr, nullptr,
                                                 nullptr, nullptr, nullptr, nullptr,
                                                 abuf, nullptr, nullptr);
  k_gemm<2><<<2048, 256, 0, stream>>>(abuf, w1, fc1b, regA, nullptr, CH_, C_, 16);
  k_gemm<3><<<512, 256, 0, stream>>>(regA, w2, fc2b, featb,
                                     (unsigned short*)pooled2, C_, CH_, 4);
  k_routing<<<16, 256, 0, stream>>>(pooled2, f2rw1w, f2rw1s, f2rw1b, f2rw2w, routing);
  // freq2 + fused residual: out = tokens + gamma2*(dft + feat)
  k_freq<<<dim3(512, 16), 256, 0, stream>>>(featb, routing, f2fw, gtab, tokens, gamma2,
                                            (float*)d_out);
}